// Round 6
// baseline (1381.950 us; speedup 1.0000x reference)
//
#include <hip/hip_runtime.h>
#include <hip/hip_bf16.h>

#define D_ 512
#define T_ 1024
#define B_ 8
#define H_ 8
#define F_ 2048
#define V_ 8192
#define L_ 6
#define NTOK 8192
#define EPS_ 1e-5f
#define NCAP 2048   // compacted-row capacity (E[NA]~737, +52 sigma)

typedef short short8 __attribute__((ext_vector_type(8)));
typedef float floatx4 __attribute__((ext_vector_type(4)));

__device__ __forceinline__ float bf2f(unsigned short u) {
  union { unsigned int i; float f; } v; v.i = ((unsigned int)u) << 16; return v.f;
}
__device__ __forceinline__ unsigned short f2bf(float f) {
  unsigned int u = __float_as_uint(f);
  return (unsigned short)((u + 0x7fffu + ((u >> 16) & 1u)) >> 16);
}
__device__ __forceinline__ float ldf(const void* p, long long i, int bf) {
  if (bf) return bf2f(((const unsigned short*)p)[i]);
  return ((const float*)p)[i];
}
// async global->LDS, 16B per lane; LDS dest = wave-uniform base + lane*16 (global addr per-lane OK)
__device__ __forceinline__ void ld16(const unsigned short* g, unsigned short* l) {
  __builtin_amdgcn_global_load_lds(
      (const __attribute__((address_space(1))) unsigned int*)g,
      (__attribute__((address_space(3))) unsigned int*)l, 16, 0, 0);
}
__device__ __forceinline__ unsigned int fkey(float f) {
  unsigned int u = __float_as_uint(f);
  return (u & 0x80000000u) ? ~u : (u ^ 0x80000000u);
}

// ---------- dtype detection (flags[0]: inputs bf16?, flags[1]: mask fmt) ----------
__global__ void detect_kernel(const unsigned int* xsw, const unsigned int* mw, int* flags) {
  __shared__ int cnt[256];
  __shared__ int m01[256], mlo[256], mhi[256];
  int tid = threadIdx.x;
  int c = 0;
  for (int t = tid; t < 1024; t += 256) {
    unsigned int lo = xsw[t] & 0xffffu;
    int ok;
    if (lo == 0u) ok = 1;
    else { unsigned int e = (lo >> 7) & 0xffu; ok = (e >= 90u && e <= 140u); }
    c += ok;
  }
  int n01 = 0, lo38 = 0, hi38 = 0;
  for (int t = tid; t < 2048; t += 256) {
    unsigned int w = mw[t];
    if (w > 1u) n01 = 1;
    if ((w & 0xffffu) == 0x3f80u) lo38 = 1;
    if ((w >> 16) == 0x3f80u) hi38 = 1;
  }
  cnt[tid] = c; m01[tid] = n01; mlo[tid] = lo38; mhi[tid] = hi38;
  __syncthreads();
  for (int s = 128; s > 0; s >>= 1) {
    if (tid < s) {
      cnt[tid] += cnt[tid + s];
      m01[tid] |= m01[tid + s]; mlo[tid] |= mlo[tid + s]; mhi[tid] |= mhi[tid + s];
    }
    __syncthreads();
  }
  if (tid == 0) {
    flags[0] = (cnt[0] > 700) ? 1 : 0;
    int fmt;
    if (!m01[0]) fmt = 0;
    else if (mlo[0]) fmt = 2;
    else if (mhi[0]) fmt = 3;
    else fmt = 1;
    flags[1] = fmt;
  }
}

// ---------- all small param vectors -> f32 P block (one launch) ----------
__global__ void conv_all_kernel(const void* d4, const void* d5, const void* d8,
                                const void* d9, const void* d12, const void* d13,
                                const void* d14, const void* d15, const void* d16,
                                float* P, const int* flags) {
  int i = blockIdx.x * 256 + threadIdx.x;
  if (i >= 14848) return;
  int bf = flags[0];
  const void* src; int off;
  if (i < 3072) { src = d4; off = 0; }
  else if (i < 6144) { src = d5; off = 3072; }
  else if (i < 9216) { src = d8; off = 6144; }
  else if (i < 12288) { src = d9; off = 9216; }
  else if (i < 12800) { src = d12; off = 12288; }
  else if (i < 13312) { src = d13; off = 12800; }
  else if (i < 13824) { src = d14; off = 13312; }
  else if (i < 14336) { src = d15; off = 13824; }
  else { src = d16; off = 14336; }
  P[i] = ldf(src, i - off, bf);
}

__global__ void convb_kernel(const void* src, unsigned short* dst, int n, const int* flags) {
  int i = blockIdx.x * 256 + threadIdx.x;
  if (i < n) {
    if (flags[0]) dst[i] = ((const unsigned short*)src)[i];
    else dst[i] = f2bf(((const float*)src)[i]);
  }
}

// ---------- weight convert + transpose: src [batch][K][N] -> dst [batch][N][K] bf16 ----------
__global__ __launch_bounds__(256) void trans_kernel(const void* src, unsigned short* dst,
                                                    int K, int N, const int* flags) {
  int bf = flags[0];
  __shared__ unsigned short tile[32][33];
  int n0 = blockIdx.x * 32, k0 = blockIdx.y * 32, batch = blockIdx.z;
  long long sbase = (long long)batch * K * N;
  long long dbase = (long long)batch * N * K;
  int c = threadIdx.x & 31, r8 = threadIdx.x >> 5;
#pragma unroll
  for (int rr = 0; rr < 4; ++rr) {
    int r = r8 + rr * 8;
    tile[r][c] = f2bf(ldf(src, sbase + (long long)(k0 + r) * N + n0 + c, bf));
  }
  __syncthreads();
#pragma unroll
  for (int rr = 0; rr < 4; ++rr) {
    int nn = r8 + rr * 8;
    dst[dbase + (long long)(n0 + nn) * K + k0 + c] = tile[c][nn];
  }
}

// ---------- big [512][8192] transposes (TOPT z=0, EMBT z=1) + fused enorm ----------
__global__ __launch_bounds__(256) void trans_big_kernel(const void* top, const void* emb,
                                                        unsigned short* TOPT, unsigned short* EMBT,
                                                        float* en, const int* flags) {
  int bf = flags[0];
  __shared__ unsigned short tile[32][33];
  int n0 = blockIdx.x * 32, k0 = blockIdx.y * 32, z = blockIdx.z;
  const void* src = z ? emb : top;
  unsigned short* dst = z ? EMBT : TOPT;
  int c = threadIdx.x & 31, r8 = threadIdx.x >> 5;
#pragma unroll
  for (int rr = 0; rr < 4; ++rr) {
    int r = r8 + rr * 8;
    tile[r][c] = f2bf(ldf(src, (long long)(k0 + r) * V_ + n0 + c, bf));
  }
  __syncthreads();
#pragma unroll
  for (int rr = 0; rr < 4; ++rr) {
    int nn = r8 + rr * 8;
    dst[(long long)(n0 + nn) * D_ + k0 + c] = tile[c][nn];
  }
  if (z == 1 && threadIdx.x < 32) {
    int nn = threadIdx.x;
    float s = 0.f;
#pragma unroll
    for (int r = 0; r < 32; ++r) { float x = bf2f(tile[r][nn]); s += x * x; }
    atomicAdd(&en[n0 + nn], s);
  }
}

// ---------- mask / pad prep + active-token compaction ----------
__global__ void prep_kernel(const void* mask, const int* lens, int* maski, float* mcomb,
                            int* idx, int* cnt, const int* flags) {
  int i = blockIdx.x * 256 + threadIdx.x;
  if (i >= NTOK) return;
  int fmt = flags[1];
  int mi;
  if (fmt == 0) mi = ((const int*)mask)[i] != 0;
  else if (fmt == 1) mi = ((const unsigned char*)mask)[i] != 0;
  else if (fmt == 2) mi = ((const unsigned short*)mask)[i] != 0;
  else mi = ((const float*)mask)[i] != 0.f;
  int b = i >> 10, t = i & (T_ - 1);
  int act = mi && (t < lens[b]);
  maski[i] = mi;
  mcomb[i] = act ? 1.f : 0.f;
  if (act) {
    int p = atomicAdd(cnt, 1);
    if (p < NCAP) idx[p] = i;
  }
}

// ---------- depth-2 pipelined MFMA K-loop core (3 LDS buffers, counted vmcnt) ----------
// T2 bank-conflict swizzle: rows are 64B (BK=32 bf16) so bank-quad = (row&1, col16);
// XOR the 16B column slot with (row>>1)&3 -> (row&1, col16^((row>>1)&3)) covers all 8
// bank-quads exactly 2x per quad-group (2-way = free). Applied BOTH sides (rule #21):
// pre-swizzled GLOBAL source in stage_tile (ld16 writes linearly) + swizzled ds_read.
// kofs/Klen support split-K (stride stays Kdim, loop covers [kofs, kofs+Klen)).
#define BK 32

template<int BN>   // 128 or 64 (B-tile width)
__device__ __forceinline__ void stage_tile(const unsigned short* A, long long ga0, long long ga1,
                                           const unsigned short* BT, long long gb0, long long gb1,
                                           int k0, unsigned short (*Ab)[BK],
                                           unsigned short (*Bb)[BK], int wave, int sw8) {
  ld16(A + ga0 + k0 + sw8, &Ab[wave * 32][0]);
  ld16(A + ga1 + k0 + sw8, &Ab[wave * 32 + 16][0]);
  if constexpr (BN == 128) {
    ld16(BT + gb0 + k0 + sw8, &Bb[wave * 32][0]);
    ld16(BT + gb1 + k0 + sw8, &Bb[wave * 32 + 16][0]);
  } else {
    ld16(BT + gb0 + k0 + sw8, &Bb[wave * 16][0]);
  }
}

// ga0/ga1: per-lane global element offsets of this wave's two A sub-rows (row*Kdim),
// computed by caller (supports gathered rows). As: [3*128][BK], Bs: [3*BN][BK].
template<int BN>
__device__ __forceinline__ void mfma_pipe(const unsigned short* A, long long ga0, long long ga1,
                                          const unsigned short* BT, int n0, int Kdim,
                                          int kofs, int Klen,
                                          unsigned short (*As)[BK], unsigned short (*Bs)[BK],
                                          floatx4 (*acc)[BN / 32], int tid) {
  constexpr int NB = BN / 32;               // B fragments per wave
  int wave = tid >> 6, lane = tid & 63;
  int r16 = lane >> 2, c16 = lane & 3;
  int lrow = lane & 15, quad = lane >> 4;
  int wm = (wave & 1) * 64, wn = (wave >> 1) * (BN / 2);
  int NT = Klen / BK;
  int sw8 = (c16 ^ ((r16 >> 1) & 3)) * 8;   // pre-swizzled global k-chunk (involution)
  int swr = (quad ^ ((lrow >> 1) & 3)) * 8; // swizzled ds_read column
  long long gb0, gb1 = 0;
  if constexpr (BN == 128) {
    gb0 = (long long)(n0 + wave * 32 + r16) * Kdim;
    gb1 = gb0 + 16LL * Kdim;
  } else {
    gb0 = (long long)(n0 + wave * 16 + r16) * Kdim;
  }
  ga0 += kofs; ga1 += kofs; gb0 += kofs; gb1 += kofs;
  // prologue: stage tiles 0 and 1
  stage_tile<BN>(A, ga0, ga1, BT, gb0, gb1, 0, As, Bs, wave, sw8);
  stage_tile<BN>(A, ga0, ga1, BT, gb0, gb1, BK, As + 128, Bs + BN, wave, sw8);
  int cur = 0, nxt = 2;
  for (int t = 0; t < NT; ++t) {
    // drain tile t's loads (own); leave tile t+1's in flight
    if (t == NT - 1) {
      asm volatile("s_waitcnt vmcnt(0)" ::: "memory");
    } else {
      if constexpr (BN == 128) asm volatile("s_waitcnt vmcnt(4)" ::: "memory");
      else                     asm volatile("s_waitcnt vmcnt(3)" ::: "memory");
    }
    __builtin_amdgcn_s_barrier();          // all waves' tile-t stages now visible
    if (t + 2 < NT)
      stage_tile<BN>(A, ga0, ga1, BT, gb0, gb1, (t + 2) * BK,
                     As + nxt * 128, Bs + nxt * BN, wave, sw8);
    unsigned short (*Ac)[BK] = As + cur * 128;
    unsigned short (*Bc)[BK] = Bs + cur * BN;
    short8 af[4], bfr[NB];
#pragma unroll
    for (int i = 0; i < 4; ++i) af[i] = *(const short8*)&Ac[wm + i * 16 + lrow][swr];
#pragma unroll
    for (int j = 0; j < NB; ++j) bfr[j] = *(const short8*)&Bc[wn + j * 16 + lrow][swr];
#pragma unroll
    for (int i = 0; i < 4; ++i)
#pragma unroll
      for (int j = 0; j < NB; ++j)
        acc[i][j] = __builtin_amdgcn_mfma_f32_16x16x32_bf16(af[i], bfr[j], acc[i][j], 0, 0, 0);
    cur = (cur == 2) ? 0 : cur + 1;
    nxt = (nxt == 2) ? 0 : nxt + 1;
  }
  __syncthreads();   // protect LDS (union reuse / last-tile reads) before epilogue
}

// ---------- 128x128 MFMA GEMM (linear grid, XCD-swizzled: m0 = bid&63) ----------
// relu->bf16 (FF1)
__global__ __launch_bounds__(256) void mgemm_kernel(const unsigned short* A,
    const unsigned short* BT, long long boff, unsigned short* Cb, int Ndim, int Kdim) {
  __shared__ __align__(16) unsigned short As[3 * 128][BK];
  __shared__ __align__(16) unsigned short Bs[3 * 128][BK];
  int tid = threadIdx.x;
  int bid = blockIdx.x;
  int m0 = (bid & 63) * 128, n0 = (bid >> 6) * 128;
  int wave = tid >> 6, lane = tid & 63;
  int wm = (wave & 1) * 64, wn = (wave >> 1) * 64;
  int lrow = lane & 15, quad = lane >> 4;
  int r16 = lane >> 2;
  floatx4 acc[4][4];
#pragma unroll
  for (int i = 0; i < 4; ++i)
#pragma unroll
    for (int j = 0; j < 4; ++j) acc[i][j] = (floatx4){0.f, 0.f, 0.f, 0.f};
  long long ga0 = (long long)(m0 + wave * 32 + r16) * Kdim;
  long long ga1 = ga0 + 16LL * Kdim;
  mfma_pipe<128>(A, ga0, ga1, BT + boff, n0, Kdim, 0, Kdim, As, Bs, acc, tid);
#pragma unroll
  for (int i = 0; i < 4; ++i) {
    int mb = m0 + wm + i * 16 + quad * 4;
#pragma unroll
    for (int j = 0; j < 4; ++j) {
      int ncol = n0 + wn + j * 16 + lrow;
#pragma unroll
      for (int r = 0; r < 4; ++r)
        Cb[(long long)(mb + r) * Ndim + ncol] = f2bf(fmaxf(acc[i][j][r], 0.f));
    }
  }
}

// ---------- 128x64 MFMA GEMM ----------
// mode: 0 f32 store, 1 f32 add into Cf, 3 +PE f32 store, 4 bf16 store,
//       5 split-K=2 atomic f32 add (grid 2x: bid>>6 = n-tile | split<<3)
__global__ __launch_bounds__(256) void mgemm64_kernel(const unsigned short* A,
    const unsigned short* BT, long long boff, float* Cf, unsigned short* Cb,
    int Ndim, int Kdim, int mode) {
  __shared__ __align__(16) unsigned short As[3 * 128][BK];
  __shared__ __align__(16) unsigned short Bs[3 * 64][BK];
  int tid = threadIdx.x;
  int bid = blockIdx.x;
  int m0 = (bid & 63) * 128;
  int nt = bid >> 6;
  int n0, kofs, Klen;
  if (mode == 5) { n0 = (nt & 7) * 64; kofs = (nt >> 3) * (Kdim >> 1); Klen = Kdim >> 1; }
  else { n0 = nt * 64; kofs = 0; Klen = Kdim; }
  int wave = tid >> 6, lane = tid & 63;
  int r16 = lane >> 2;
  int wm = (wave & 1) * 64, wn = (wave >> 1) * 32;
  int lrow = lane & 15, quad = lane >> 4;
  floatx4 acc[4][2];
#pragma unroll
  for (int i = 0; i < 4; ++i)
#pragma unroll
    for (int j = 0; j < 2; ++j) acc[i][j] = (floatx4){0.f, 0.f, 0.f, 0.f};
  long long ga0 = (long long)(m0 + wave * 32 + r16) * Kdim;
  long long ga1 = ga0 + 16LL * Kdim;
  mfma_pipe<64>(A, ga0, ga1, BT + boff, n0, Kdim, kofs, Klen, As, Bs, acc, tid);
#pragma unroll
  for (int i = 0; i < 4; ++i) {
    int mb = m0 + wm + i * 16 + quad * 4;
#pragma unroll
    for (int j = 0; j < 2; ++j) {
      int ncol = n0 + wn + j * 16 + lrow;
#pragma unroll
      for (int r = 0; r < 4; ++r) {
        int m = mb + r;
        long long idx = (long long)m * Ndim + ncol;
        float v = acc[i][j][r];
        if (mode == 1) Cf[idx] += v;
        else if (mode == 5) atomicAdd(&Cf[idx], v);
        else if (mode == 4) Cb[idx] = f2bf(v);
        else if (mode == 3) {
          int t = m & (T_ - 1);
          float freq = __expf(-(float)(ncol & ~1) * (9.210340371976184f / (float)D_));
          float ang = (float)t * freq;
          v += (ncol & 1) ? cosf(ang) : sinf(ang);
          Cf[idx] = v;
        } else Cf[idx] = v;
      }
    }
  }
}

// ---------- QKV GEMM: Q direct; K/V via LDS transpose -> coalesced tile stores ----------
__global__ __launch_bounds__(256) void qkvgemm_kernel(const unsigned short* A,
    const unsigned short* BT, long long boff, unsigned short* QB,
    unsigned short* KSg, unsigned short* VTSg) {
  __shared__ __align__(16) union {
    struct { unsigned short As[3 * 128][BK]; unsigned short Bs[3 * 128][BK]; } s;
    unsigned short T[128][136];
  } sm;
  int tid = threadIdx.x;
  int bid = blockIdx.x;
  int m0 = (bid & 63) * 128;
  int nt = bid >> 6;
  int n0 = nt * 128;
  int wave = tid >> 6, lane = tid & 63;
  int wm = (wave & 1) * 64, wn = (wave >> 1) * 64;
  int lrow = lane & 15, quad = lane >> 4;
  int r16 = lane >> 2;
  floatx4 acc[4][4];
#pragma unroll
  for (int i = 0; i < 4; ++i)
#pragma unroll
    for (int j = 0; j < 4; ++j) acc[i][j] = (floatx4){0.f, 0.f, 0.f, 0.f};
  long long ga0 = (long long)(m0 + wave * 32 + r16) * D_;
  long long ga1 = ga0 + 16LL * D_;
  mfma_pipe<128>(A, ga0, ga1, BT + boff, n0, D_, 0, D_, sm.s.As, sm.s.Bs, acc, tid);
  int b = m0 >> 10, tt = (m0 >> 7) & 7;
  if (nt < 4) {
#pragma unroll
    for (int i = 0; i < 4; ++i) {
      int mb = m0 + wm + i * 16 + quad * 4;
#pragma unroll
      for (int j = 0; j < 4; ++j) {
        int ncol = n0 + wn + j * 16 + lrow;
#pragma unroll
        for (int r = 0; r < 4; ++r)
          QB[(long long)(mb + r) * 512 + ncol] = f2bf(acc[i][j][r]);
      }
    }
  } else if (nt < 8) {
#pragma unroll
    for (int i = 0; i < 4; ++i)
#pragma unroll
      for (int j = 0; j < 4; ++j)
#pragma unroll
        for (int r = 0; r < 4; ++r)
          sm.T[wm + i * 16 + quad * 4 + r][wn + j * 16 + lrow] = f2bf(acc[i][j][r]);
    __syncthreads();
    int tk = tid & 127, hg0 = tid >> 7;
#pragma unroll
    for (int p = 0; p < 8; ++p) {
      int hg = p * 2 + hg0;
      int h2 = hg >> 3, g = hg & 7;
      uint4 u = *(const uint4*)&sm.T[tk][h2 * 64 + g * 8];
      int headg = (nt - 4) * 2 + h2;
      long long dst = (((((long long)(b * 8 + headg)) * 8 + tt) * 8 + g) * 128 + tk) * 8;
      *(uint4*)&KSg[dst] = u;
    }
  } else {
#pragma unroll
    for (int i = 0; i < 4; ++i)
#pragma unroll
      for (int j = 0; j < 4; ++j)
#pragma unroll
        for (int r = 0; r < 4; ++r)
          sm.T[wn + j * 16 + lrow][wm + i * 16 + quad * 4 + r] = f2bf(acc[i][j][r]);
    __syncthreads();
    int col = tid & 127, gh = tid >> 7;
    int h2 = col >> 6, ch = col & 63;
    int headg = (nt - 8) * 2 + h2;
    long long base = ((((long long)(b * 8 + headg)) * 8 + tt) * 16);
#pragma unroll
    for (int p = 0; p < 8; ++p) {
      int g = p * 2 + gh;
      uint4 u = *(const uint4*)&sm.T[col][g * 8];
      long long dst = ((base + g) * 64 + ch) * 8;
      *(uint4*)&VTSg[dst] = u;
    }
  }
}

// ---------- flash MFMA attention: barrier-free, early-issue load schedule ----------
// Round-2 structure with load issue points hoisted so every global load has a
// VALU/MFMA phase covering its latency (T14). Proven: 1287us total, fattn <46us.
__global__ __launch_bounds__(256) void fattn_kernel(const unsigned short* QB,
    const unsigned short* KSg, const unsigned short* VTSg, const int* lens,
    unsigned short* ao) {
  __shared__ __align__(16) unsigned short Ps[64 * 128];
  int blk = blockIdx.x;                     // 1024 blocks = 16 qt x 64 bh
  int swz = (blk & 7) * 128 + (blk >> 3);   // XCD-contiguous: 128 logical blocks/XCD
  int qt = swz & 15, bh = swz >> 4;
  int b = bh >> 3, h = bh & 7;
  int tid = threadIdx.x, wave = tid >> 6, lane = tid & 63;
  int c = lane & 15, quad = lane >> 4;
  int len = lens[b];
  short8 qf[2];
#pragma unroll
  for (int ks = 0; ks < 2; ++ks)
    qf[ks] = *(const short8*)&QB[(long long)(b * 1024 + qt * 64 + wave * 16 + c) * 512
                                 + h * 64 + ks * 32 + quad * 8];
  floatx4 accO[4];
  float lr[4];
#pragma unroll
  for (int j = 0; j < 4; ++j) { accO[j] = (floatx4){0.f, 0.f, 0.f, 0.f}; lr[j] = 0.f; }
  int nkt = (len + 127) >> 7;
  const unsigned short* kp = KSg + (long long)bh * 65536;
  const unsigned short* vp = VTSg + (long long)bh * 65536;
  int kb = (quad * 128 + c) * 8;            // K frag base; +j*128 per j, +4096 for hb=1
  int vbase = quad * 512 + c * 8;           // V frag base; +X*2048 +jn*128
  int row = wave * 16 + c;
  short8 kA[8], kB[8], vA[8], vB[8];
  // preload K(kt=0) jh0 -> kA
#pragma unroll
  for (int j2 = 0; j2 < 4; ++j2) {
    kA[j2]     = *(const short8*)&kp[kb + j2 * 128];
    kA[4 + j2] = *(const short8*)&kp[kb + 4096 + j2 * 128];
  }
  for (int kt = 0; kt < nkt; ++kt) {
    int kbase = kt * 128;
    const unsigned short* kpc = kp + kt * 8192;
    const unsigned short* vpc = vp + kt * 8192;
    const unsigned short* kpn = kpc + 8192;
    int more = (kt + 1 < nkt);
    // issue K jh1 -> kB (covered by QK jh0 + softmax jh0)
#pragma unroll
    for (int j2 = 0; j2 < 4; ++j2) {
      kB[j2]     = *(const short8*)&kpc[kb + (4 + j2) * 128];
      kB[4 + j2] = *(const short8*)&kpc[kb + 4096 + (4 + j2) * 128];
    }
    // ---- QK jh0 (kA) ----
    floatx4 s0[4];
#pragma unroll
    for (int j2 = 0; j2 < 4; ++j2) s0[j2] = (floatx4){0.f, 0.f, 0.f, 0.f};
#pragma unroll
    for (int j2 = 0; j2 < 4; ++j2) {
      s0[j2] = __builtin_amdgcn_mfma_f32_16x16x32_bf16(qf[0], kA[j2], s0[j2], 0, 0, 0);
      s0[j2] = __builtin_amdgcn_mfma_f32_16x16x32_bf16(qf[1], kA[4 + j2], s0[j2], 0, 0, 0);
    }
    // issue V kh0 -> vA (covered by softmax jh0 + QK jh1)
#pragma unroll
    for (int q = 0; q < 8; ++q)
      vA[q] = *(const short8*)&vpc[(q >> 2) * 2048 + (q & 3) * 128 + vbase];
    // softmax jh0 -> Ps cols 0..63
#pragma unroll
    for (int r = 0; r < 4; ++r) {
      int prow = wave * 16 + quad * 4 + r;
      int rx = quad * 4 + r;
#pragma unroll
      for (int j2 = 0; j2 < 4; ++j2) {
        int col = j2 * 16 + c;
        float s = s0[j2][r] * 0.125f;
        s = (kbase + col < len) ? s : -100.f;
        float p = __expf(s);
        lr[r] += p;
        Ps[prow * 128 + (((col >> 3) ^ rx) * 8) + (col & 7)] = f2bf(p);
      }
    }
    // ---- QK jh1 (kB) ----
    floatx4 s1[4];
#pragma unroll
    for (int j2 = 0; j2 < 4; ++j2) s1[j2] = (floatx4){0.f, 0.f, 0.f, 0.f};
#pragma unroll
    for (int j2 = 0; j2 < 4; ++j2) {
      s1[j2] = __builtin_amdgcn_mfma_f32_16x16x32_bf16(qf[0], kB[j2], s1[j2], 0, 0, 0);
      s1[j2] = __builtin_amdgcn_mfma_f32_16x16x32_bf16(qf[1], kB[4 + j2], s1[j2], 0, 0, 0);
    }
    // issue V kh1 -> vB (covered by softmax jh1)
#pragma unroll
    for (int q = 0; q < 8; ++q)
      vB[q] = *(const short8*)&vpc[(2 + (q >> 2)) * 2048 + (q & 3) * 128 + vbase];
    // softmax jh1 -> Ps cols 64..127
#pragma unroll
    for (int r = 0; r < 4; ++r) {
      int prow = wave * 16 + quad * 4 + r;
      int rx = quad * 4 + r;
#pragma unroll
      for (int j2 = 0; j2 < 4; ++j2) {
        int col = (4 + j2) * 16 + c;
        float s = s1[j2][r] * 0.125f;
        s = (kbase + col < len) ? s : -100.f;
        float p = __expf(s);
        lr[r] += p;
        Ps[prow * 128 + (((col >> 3) ^ rx) * 8) + (col & 7)] = f2bf(p);
      }
    }
    // ---- PV kh0 (vA) ----
#pragma unroll
    for (int kk2 = 0; kk2 < 2; ++kk2) {
      short8 pa = *(const short8*)&Ps[row * 128 + (((kk2 * 4 + quad) ^ c) * 8)];
#pragma unroll
      for (int jn = 0; jn < 4; ++jn)
        accO[jn] = __builtin_amdgcn_mfma_f32_16x16x32_bf16(pa, vA[kk2 * 4 + jn], accO[jn], 0, 0, 0);
    }
    // issue next K jh0 -> kA (vA dead; covered by PV kh1)
    if (more) {
#pragma unroll
      for (int j2 = 0; j2 < 4; ++j2) {
        kA[j2]     = *(const short8*)&kpn[kb + j2 * 128];
        kA[4 + j2] = *(const short8*)&kpn[kb + 4096 + j2 * 128];
      }
    }
    // ---- PV kh1 (vB) ----
#pragma unroll
    for (int kk2 = 0; kk2 < 2; ++kk2) {
      int kk = 2 + kk2;
      short8 pa = *(const short8*)&Ps[row * 128 + (((kk * 4 + quad) ^ c) * 8)];
#pragma unroll
      for (int jn = 0; jn < 4; ++jn)
        accO[jn] = __builtin_amdgcn_mfma_f32_16x16x32_bf16(pa, vB[kk2 * 4 + jn], accO[jn], 0, 0, 0);
    }
  }
  // deferred row-reduce, normalize + store
#pragma unroll
  for (int r = 0; r < 4; ++r) {
    float ls = lr[r];
    ls += __shfl_xor(ls, 1, 64);
    ls += __shfl_xor(ls, 2, 64);
    ls += __shfl_xor(ls, 4, 64);
    ls += __shfl_xor(ls, 8, 64);
    float inv = 1.f / ls;
    long long token = b * 1024 + qt * 64 + wave * 16 + quad * 4 + r;
#pragma unroll
    for (int jn = 0; jn < 4; ++jn)
      ao[token * 512 + h * 64 + jn * 16 + c] = f2bf(accO[jn][r] * inv);
  }
}

// ---------- argmin GEMM over COMPACTED rows: dist = enorm[v] - 2*(Z[idx].ET^T) ----------
__global__ __launch_bounds__(256) void dgemm_argmin(const unsigned short* Z, const int* ridx,
    const int* cnt, const unsigned short* ET, const float* en, unsigned long long* best) {
  __shared__ __align__(16) union {
    struct { unsigned short A[3 * 128][BK]; unsigned short B[3 * 128][BK]; } s;
    unsigned long long part[128][33];
  } sm;
  int m0 = blockIdx.y * 128;
  int na = *cnt;
  if (m0 >= ((na + 127) & ~127)) return;
  int tid = threadIdx.x;
  int n0 = blockIdx.x * 128;
  int wave = tid >> 6, lane = tid & 63;
  int wm = (wave & 1) * 64, wn = (wave >> 1) * 64;
  int lrow = lane & 15, quad = lane >> 4;
  int r16 = lane >> 2;
  int slot = (wave >> 1) * 16 + lrow;
  floatx4 acc[4][4];
#pragma unroll
  for (int i = 0; i < 4; ++i)
#pragma unroll
    for (int j = 0; j < 4; ++j) acc[i][j] = (floatx4){0.f, 0.f, 0.f, 0.f};
  long long ga0 = (long long)ridx[m0 + wave * 32 + r16] * D_;
  long long ga1 = (long long)ridx[m0 + wave * 32 + 16 + r16] * D_;
  mfma_pipe<128>(Z, ga0, ga1, ET, n0, D_, 0, D_, sm.s.A, sm.s.B, acc, tid);
  float env[4];
#pragma unroll
  for (int j = 0; j < 4; ++j) env[j] = en[n0 + wn + j * 16 + lrow];
#pragma unroll
  for (int i = 0; i < 4; ++i) {
#pragma unroll
    for (int r = 0; r < 4; ++r) {
      int rowl = wm + i * 16 + quad * 4 + r;
      unsigned long long bl = ~0ull;
#pragma unroll
      for (int j = 0; j < 4; ++j) {
        float v = env[j] - 2.f * acc[i][j][r];
        unsigned long long pk = (((unsigned long long)fkey(v)) << 32) |
                                (unsigned int)(n0 + wn + j * 16 + lrow);
        if (pk < bl) bl = pk;
      }
      sm.part[rowl][(slot + rowl) & 31] = bl;
    }
  }
  __syncthreads();
  if (tid < 128) {
    unsigned long long bb = sm.part[tid][0];
#pragma unroll 4
    for (int k2 = 1; k2 < 32; ++k2) { unsigned long long o = sm.part[tid][k2]; if (o < bb) bb = o; }
    atomicMin(&best[m0 + tid], bb);
  }
}

// ---------- logits GEMM over COMPACTED rows: fixed-offset LSE + target logit ----------
__global__ __launch_bounds__(256) void lgemm_lse(const unsigned short* OUTB, const int* ridx,
    const int* cnt, const unsigned short* TOPT, const unsigned long long* best,
    float* PS, float* TL) {
  __shared__ __align__(16) union {
    struct { unsigned short A[3 * 128][BK]; unsigned short B[3 * 128][BK]; } s;
    float part[128][33];
  } sm;
  int m0 = blockIdx.y * 128;
  int na = *cnt;
  if (m0 >= ((na + 127) & ~127)) return;
  int tid = threadIdx.x;
  int n0 = blockIdx.x * 128;
  int wave = tid >> 6, lane = tid & 63;
  int wm = (wave & 1) * 64, wn = (wave >> 1) * 64;
  int lrow = lane & 15, quad = lane >> 4;
  int r16 = lane >> 2;
  int slot = (wave >> 1) * 16 + lrow;
  floatx4 acc[4][4];
#pragma unroll
  for (int i = 0; i < 4; ++i)
#pragma unroll
    for (int j = 0; j < 4; ++j) acc[i][j] = (floatx4){0.f, 0.f, 0.f, 0.f};
  long long ga0 = (long long)ridx[m0 + wave * 32 + r16] * D_;
  long long ga1 = (long long)ridx[m0 + wave * 32 + 16 + r16] * D_;
  mfma_pipe<128>(OUTB, ga0, ga1, TOPT, n0, D_, 0, D_, sm.s.A, sm.s.B, acc, tid);
#pragma unroll
  for (int i = 0; i < 4; ++i) {
#pragma unroll
    for (int r = 0; r < 4; ++r) {
      int rowl = wm + i * 16 + quad * 4 + r;
      int tg = (int)(best[m0 + rowl] & 0xffffffffu);
      float ss = 0.f;
#pragma unroll
      for (int j = 0; j < 4; ++j) {
        float v = acc[i][j][r];
        ss += __expf(v);
        if (n0 + wn + j * 16 + lrow == tg) TL[m0 + rowl] = v;
      }
      sm.part[rowl][(slot + rowl) & 31] = ss;
    }
  }
  __syncthreads();
  if (tid < 128) {
    float S = 0.f;
#pragma unroll 4
    for (int k2 = 0; k2 < 32; ++k2) S += sm.part[tid][k2];
    PS[(long long)(m0 + tid) * 64 + blockIdx.x] = S;
  }
}

__global__ void lse_combine(const float* PS, const float* TL, const int* cnt, float* entm) {
  int t = blockIdx.x * 256 + threadIdx.x;   // compact index, grid covers NCAP
  if (t >= NCAP) return;
  if (t < *cnt) {
    float S = 0.f;
    for (int i = 0; i < 64; ++i) S += PS[(long long)t * 64 + i];
    entm[t] = __logf(S) - TL[t];            // mcomb == 1 for active rows
  } else {
    entm[t] = 0.f;
  }
}

// ---------- layernorm: wave per token, shuffle reductions ----------
__global__ __launch_bounds__(256) void ln_kernel(const float* X, float* Yf, unsigned short* Yb,
                                                 int obf, const float* s, const float* b) {
  int tid = threadIdx.x, wave = tid >> 6, lane = tid & 63;
  long long n = (long long)blockIdx.x * 4 + wave;
  const float* x = X + n * D_ + lane * 8;
  float v[8];
  *(float4*)&v[0] = *(const float4*)x;
  *(float4*)&v[4] = *(const float4*)(x + 4);
  float sum = 0.f;
#pragma unroll
  for (int j = 0; j < 8; ++j) sum += v[j];
  for (int m = 32; m; m >>= 1) sum += __shfl_xor(sum, m, 64);
  float mean = sum * (1.f / (float)D_);
  float vs = 0.f;
#pragma unroll
  for (int j = 0; j < 8; ++j) { v[j] -= mean; vs += v[j] * v[j]; }
  for (int m = 32; m; m >>= 1) vs += __shfl_xor(vs, m, 64);
  float r = rsqrtf(vs * (1.f / (float)D_) + EPS_);
  float sv[8], bv[8];
  *(float4*)&sv[0] = *(const float4*)(s + lane * 8);
  *(float4*)&sv[4] = *(const float4*)(s + lane * 8 + 4);
  *(float4*)&bv[0] = *(const float4*)(b + lane * 8);
  *(float4*)&bv[4] = *(const float4*)(b + lane * 8 + 4);
  if (obf) {
    unsigned short o[8];
#pragma unroll
    for (int j = 0; j < 8; ++j) o[j] = f2bf(v[j] * r * sv[j] + bv[j]);
    *(uint4*)(Yb + n * D_ + lane * 8) = *(const uint4*)o;
  } else {
    float o[8];
#pragma unroll
    for (int j = 0; j < 8; ++j) o[j] = v[j] * r * sv[j] + bv[j];
    *(float4*)(Yf + n * D_ + lane * 8) = *(const float4*)&o[0];
    *(float4*)(Yf + n * D_ + lane * 8 + 4) = *(const float4*)&o[4];
  }
}

// ---------- masked_xs ----------
__global__ void maskapply_kernel(float* x, const int* maski, const float* memb) {
  long long i = (long long)blockIdx.x * 256 + threadIdx.x;
  int n = (int)(i >> 9), d = (int)(i & 511);
  if (maski[n]) x[i] = memb[d];
}

// ---------- final reduce + dual-dtype write ----------
__global__ void final_kernel(const float* entm, const float* mcomb, void* out) {
  __shared__ float r1[256], r2[256];
  int tid = threadIdx.x;
  float s1 = 0.f, s2 = 0.f;
  for (int i = tid; i < NCAP; i += 256) s1 += entm[i];
  for (int i = tid; i < NTOK; i += 256) s2 += mcomb[i];
  r1[tid] = s1; r2[tid] = s2;
  __syncthreads();
  for (int st = 128; st > 0; st >>= 1) {
    if (tid < st) { r1[tid] += r1[tid + st]; r2[tid] += r2[tid + st]; }
    __syncthreads();
  }
  if (tid == 0) {
    float loss = r1[0] / r2[0];
    unsigned short b16 = f2bf(loss);
    unsigned short* o = (unsigned short*)out;
    o[0] = b16; o[1] = b16;
  }
}

extern "C" void kernel_launch(void* const* d_in, const int* in_sizes, int n_in,
                              void* d_out, int out_size, void* d_ws, size_t ws_size,
                              hipStream_t stream) {
  if (n_in < 20) return;
  float* wsf = (float*)d_ws;
  int* flags = (int*)d_ws;
  const long long OF_P = 256;
  const long long OF_X = 16640;
  const long long OF_HB = OF_X + 4194304;
  const long long OF_BIG = OF_HB + 2097152;
  const long long OF_AOB = OF_BIG + 8388608;
  const long long OF_WT = OF_AOB + 2097152;
  const long long OF_TOPT = OF_WT + 9699328;
  const long long OF_EMBT = OF_TOPT + 2097152;
  const long long OF_EN = OF_EMBT + 2097152;
  const long long OF_BEST = OF_EN + 8192;          // NCAP u64 = 4096 floats
  const long long OF_PS = OF_BEST + 4096;          // NCAP*64 floats
  const long long OF_TL = OF_PS + 131072;          // NCAP
  const long long OF_MI = OF_TL + 2048;
  const long long OF_MC = OF_MI + 8192;
  const long long OF_EM = OF_MC + 8192;            // NCAP
  const long long OF_CNT = OF_EM + 2048;
  const long long OF_IDX = OF_CNT + 16;            // NCAP ints
  const long long END = OF_IDX + 2048;
  if (ws_size < (size_t)END * 4) return;

  float* X = wsf + OF_X;
  unsigned short* HB = (unsigned short*)(wsf + OF_HB);
  unsigned short* BIGB = (unsigned short*)(wsf + OF_BIG);
  unsigned short* AOB = (unsigned short*)(wsf + OF_AOB);
  unsigned short* WT = (unsigned short*)(wsf + OF_WT);
  unsigned short* TOPT = (unsigned short*)(wsf + OF_TOPT);
  unsigned short* EMBT = (unsigned short*)(wsf + OF_EMBT);
  float* EN = wsf + OF_EN;
  unsigned long long* BEST = (unsigned long long*)(wsf + OF_BEST);
  float* PS = wsf + OF_PS;
  float* TL = wsf + OF_TL;
  int* MI = (int*)(wsf + OF_MI);
  float* MC = wsf + OF_MC;
  float* EM = wsf + OF_EM;
  int* CNT = (int*)(wsf + OF_CNT);
  int* IDX = (int*)(wsf + OF_IDX);
  float* P = wsf + OF_P;
  float* ln1s = P, *ln1b = P + 3072, *ln2s = P + 6144, *ln2b = P + 9216;
  float* ans = P + 12288, *anb = P + 12800, *ilns = P + 13312, *ilnb = P + 13824;
  float* memb = P + 14336;

  unsigned short* QB = BIGB;
  unsigned short* KSg = BIGB + 4194304;
  unsigned short* VTSg = BIGB + 8388608;

  const long long W_QKV = 0, W_O = 4718592, W_1 = 6291456, W_2 = 12582912,
                  W_EMB = 18874368, W_PRJ = 19136512;

  detect_kernel<<<1, 256, 0, stream>>>((const unsigned int*)d_in[0],
                                       (const unsigned int*)d_in[2], flags);
  hipMemsetAsync((void*)BEST, 0xFF, NCAP * 8, stream);
  hipMemsetAsync((void*)EN, 0, V_ * 4, stream);
  hipMemsetAsync((void*)CNT, 0, 16, stream);
  hipMemsetAsync((void*)IDX, 0, NCAP * 4, stream);
  conv_all_kernel<<<58, 256, 0, stream>>>(d_in[4], d_in[5], d_in[8], d_in[9], d_in[12],
                                          d_in[13], d_in[14], d_in[15], d_in[16], P, flags);
  prep_kernel<<<32, 256, 0, stream>>>(d_in[2], (const int*)d_in[1], MI, MC, IDX, CNT, flags);

  unsigned short* XSB = BIGB;
  convb_kernel<<<16384, 256, 0, stream>>>(d_in[0], XSB, 4194304, flags);

  trans_kernel<<<dim3(48, 16, 6), 256, 0, stream>>>(d_in[6], WT + W_QKV, 512, 1536, flags);
  trans_kernel<<<dim3(16, 16, 6), 256, 0, stream>>>(d_in[7], WT + W_O, 512, 512, flags);
  trans_kernel<<<dim3(64, 16, 6), 256, 0, stream>>>(d_in[10], WT + W_1, 512, 2048, flags);
  trans_kernel<<<dim3(16, 64, 6), 256, 0, stream>>>(d_in[11], WT + W_2, 2048, 512, flags);
  trans_kernel<<<dim3(16, 16, 1), 256, 0, stream>>>(d_in[3], WT + W_EMB, 512, 512, flags);
  trans_kernel<<<dim3(16, 16, 1), 256, 0, stream>>>(d_in[18], WT + W_PRJ, 512, 512, flags);
  trans_big_kernel<<<dim3(256, 16, 2), 256, 0, stream>>>(d_in[17], d_in[19], TOPT, EMBT,
                                                         EN, flags);

  dim3 gC(64, NCAP / 128);   // compacted V-GEMMs: 16 row-tiles, device-side early exit

  // x = xs @ W_embed + PE
  mgemm64_kernel<<<512, 256, 0, stream>>>(XSB, WT + W_EMB, 0, X, nullptr, 512, 512, 3);
  // target ids (needed only for masked&padded tokens -> compacted)
  ln_kernel<<<2048, 256, 0, stream>>>(X, nullptr, HB, 1, ilns, ilnb);
  mgemm64_kernel<<<512, 256, 0, stream>>>(HB, WT + W_PRJ, 0, nullptr, AOB, 512, 512, 4);
  dgemm_argmin<<<gC, 256, 0, stream>>>(AOB, IDX, CNT, EMBT, EN, BEST);
  maskapply_kernel<<<16384, 256, 0, stream>>>(X, MI, memb);

  for (int l = 0; l < L_; ++l) {
    ln_kernel<<<2048, 256, 0, stream>>>(X, nullptr, HB, 1, ln1s + l * 512, ln1b + l * 512);
    qkvgemm_kernel<<<768, 256, 0, stream>>>(HB, WT + W_QKV, (long long)l * 786432,
                                            QB, KSg, VTSg);
    fattn_kernel<<<1024, 256, 0, stream>>>(QB, KSg, VTSg, (const int*)d_in[1], AOB);
    mgemm64_kernel<<<512, 256, 0, stream>>>(AOB, WT + W_O, (long long)l * 262144,
                                            X, nullptr, 512, 512, 1);
    ln_kernel<<<2048, 256, 0, stream>>>(X, nullptr, HB, 1, ln2s + l * 512, ln2b + l * 512);
    mgemm_kernel<<<1024, 256, 0, stream>>>(HB, WT + W_1, (long long)l * 1048576,
                                           BIGB, 2048, 512);
    mgemm64_kernel<<<1024, 256, 0, stream>>>(BIGB, WT + W_2, (long long)l * 1048576,
                                             X, nullptr, 512, 2048, 5);
  }
  ln_kernel<<<2048, 256, 0, stream>>>(X, nullptr, AOB, 1, ans, anb);
  lgemm_lse<<<gC, 256, 0, stream>>>(AOB, IDX, CNT, TOPT, BEST, PS, TL);
  lse_combine<<<8, 256, 0, stream>>>(PS, TL, CNT, EM);
  final_kernel<<<1, 256, 0, stream>>>(EM, MC, d_out);
}

// Round 7
// 1226.486 us; speedup vs baseline: 1.1268x; 1.1268x over previous
//
#include <hip/hip_runtime.h>
#include <hip/hip_bf16.h>

#define D_ 512
#define T_ 1024
#define B_ 8
#define H_ 8
#define F_ 2048
#define V_ 8192
#define L_ 6
#define NTOK 8192
#define EPS_ 1e-5f
#define NCAP 2048   // compacted-row capacity (E[NA]~737, +52 sigma)

typedef short short8 __attribute__((ext_vector_type(8)));
typedef float floatx4 __attribute__((ext_vector_type(4)));

__device__ __forceinline__ float bf2f(unsigned short u) {
  union { unsigned int i; float f; } v; v.i = ((unsigned int)u) << 16; return v.f;
}
__device__ __forceinline__ unsigned short f2bf(float f) {
  unsigned int u = __float_as_uint(f);
  return (unsigned short)((u + 0x7fffu + ((u >> 16) & 1u)) >> 16);
}
__device__ __forceinline__ float ldf(const void* p, long long i, int bf) {
  if (bf) return bf2f(((const unsigned short*)p)[i]);
  return ((const float*)p)[i];
}
// async global->LDS, 16B per lane; LDS dest = wave-uniform base + lane*16 (global addr per-lane OK)
__device__ __forceinline__ void ld16(const unsigned short* g, unsigned short* l) {
  __builtin_amdgcn_global_load_lds(
      (const __attribute__((address_space(1))) unsigned int*)g,
      (__attribute__((address_space(3))) unsigned int*)l, 16, 0, 0);
}
__device__ __forceinline__ unsigned int fkey(float f) {
  unsigned int u = __float_as_uint(f);
  return (u & 0x80000000u) ? ~u : (u ^ 0x80000000u);
}

// ---------- dtype detection (flags[0]: inputs bf16?, flags[1]: mask fmt) ----------
__global__ void detect_kernel(const unsigned int* xsw, const unsigned int* mw, int* flags) {
  __shared__ int cnt[256];
  __shared__ int m01[256], mlo[256], mhi[256];
  int tid = threadIdx.x;
  int c = 0;
  for (int t = tid; t < 1024; t += 256) {
    unsigned int lo = xsw[t] & 0xffffu;
    int ok;
    if (lo == 0u) ok = 1;
    else { unsigned int e = (lo >> 7) & 0xffu; ok = (e >= 90u && e <= 140u); }
    c += ok;
  }
  int n01 = 0, lo38 = 0, hi38 = 0;
  for (int t = tid; t < 2048; t += 256) {
    unsigned int w = mw[t];
    if (w > 1u) n01 = 1;
    if ((w & 0xffffu) == 0x3f80u) lo38 = 1;
    if ((w >> 16) == 0x3f80u) hi38 = 1;
  }
  cnt[tid] = c; m01[tid] = n01; mlo[tid] = lo38; mhi[tid] = hi38;
  __syncthreads();
  for (int s = 128; s > 0; s >>= 1) {
    if (tid < s) {
      cnt[tid] += cnt[tid + s];
      m01[tid] |= m01[tid + s]; mlo[tid] |= mlo[tid + s]; mhi[tid] |= mhi[tid + s];
    }
    __syncthreads();
  }
  if (tid == 0) {
    flags[0] = (cnt[0] > 700) ? 1 : 0;
    int fmt;
    if (!m01[0]) fmt = 0;
    else if (mlo[0]) fmt = 2;
    else if (mhi[0]) fmt = 3;
    else fmt = 1;
    flags[1] = fmt;
  }
}

// ---------- all small param vectors -> f32 P block (one launch) ----------
__global__ void conv_all_kernel(const void* d4, const void* d5, const void* d8,
                                const void* d9, const void* d12, const void* d13,
                                const void* d14, const void* d15, const void* d16,
                                float* P, const int* flags) {
  int i = blockIdx.x * 256 + threadIdx.x;
  if (i >= 14848) return;
  int bf = flags[0];
  const void* src; int off;
  if (i < 3072) { src = d4; off = 0; }
  else if (i < 6144) { src = d5; off = 3072; }
  else if (i < 9216) { src = d8; off = 6144; }
  else if (i < 12288) { src = d9; off = 9216; }
  else if (i < 12800) { src = d12; off = 12288; }
  else if (i < 13312) { src = d13; off = 12800; }
  else if (i < 13824) { src = d14; off = 13312; }
  else if (i < 14336) { src = d15; off = 13824; }
  else { src = d16; off = 14336; }
  P[i] = ldf(src, i - off, bf);
}

__global__ void convb_kernel(const void* src, unsigned short* dst, int n, const int* flags) {
  int i = blockIdx.x * 256 + threadIdx.x;
  if (i < n) {
    if (flags[0]) dst[i] = ((const unsigned short*)src)[i];
    else dst[i] = f2bf(((const float*)src)[i]);
  }
}

// ---------- weight convert + transpose: src [batch][K][N] -> dst [batch][N][K] bf16 ----------
__global__ __launch_bounds__(256) void trans_kernel(const void* src, unsigned short* dst,
                                                    int K, int N, const int* flags) {
  int bf = flags[0];
  __shared__ unsigned short tile[32][33];
  int n0 = blockIdx.x * 32, k0 = blockIdx.y * 32, batch = blockIdx.z;
  long long sbase = (long long)batch * K * N;
  long long dbase = (long long)batch * N * K;
  int c = threadIdx.x & 31, r8 = threadIdx.x >> 5;
#pragma unroll
  for (int rr = 0; rr < 4; ++rr) {
    int r = r8 + rr * 8;
    tile[r][c] = f2bf(ldf(src, sbase + (long long)(k0 + r) * N + n0 + c, bf));
  }
  __syncthreads();
#pragma unroll
  for (int rr = 0; rr < 4; ++rr) {
    int nn = r8 + rr * 8;
    dst[dbase + (long long)(n0 + nn) * K + k0 + c] = tile[c][nn];
  }
}

// ---------- big [512][8192] transposes (TOPT z=0, EMBT z=1) + fused enorm ----------
__global__ __launch_bounds__(256) void trans_big_kernel(const void* top, const void* emb,
                                                        unsigned short* TOPT, unsigned short* EMBT,
                                                        float* en, const int* flags) {
  int bf = flags[0];
  __shared__ unsigned short tile[32][33];
  int n0 = blockIdx.x * 32, k0 = blockIdx.y * 32, z = blockIdx.z;
  const void* src = z ? emb : top;
  unsigned short* dst = z ? EMBT : TOPT;
  int c = threadIdx.x & 31, r8 = threadIdx.x >> 5;
#pragma unroll
  for (int rr = 0; rr < 4; ++rr) {
    int r = r8 + rr * 8;
    tile[r][c] = f2bf(ldf(src, (long long)(k0 + r) * V_ + n0 + c, bf));
  }
  __syncthreads();
#pragma unroll
  for (int rr = 0; rr < 4; ++rr) {
    int nn = r8 + rr * 8;
    dst[(long long)(n0 + nn) * D_ + k0 + c] = tile[c][nn];
  }
  if (z == 1 && threadIdx.x < 32) {
    int nn = threadIdx.x;
    float s = 0.f;
#pragma unroll
    for (int r = 0; r < 32; ++r) { float x = bf2f(tile[r][nn]); s += x * x; }
    atomicAdd(&en[n0 + nn], s);
  }
}

// ---------- mask / pad prep + active-token compaction ----------
__global__ void prep_kernel(const void* mask, const int* lens, int* maski, float* mcomb,
                            int* idx, int* cnt, const int* flags) {
  int i = blockIdx.x * 256 + threadIdx.x;
  if (i >= NTOK) return;
  int fmt = flags[1];
  int mi;
  if (fmt == 0) mi = ((const int*)mask)[i] != 0;
  else if (fmt == 1) mi = ((const unsigned char*)mask)[i] != 0;
  else if (fmt == 2) mi = ((const unsigned short*)mask)[i] != 0;
  else mi = ((const float*)mask)[i] != 0.f;
  int b = i >> 10, t = i & (T_ - 1);
  int act = mi && (t < lens[b]);
  maski[i] = mi;
  mcomb[i] = act ? 1.f : 0.f;
  if (act) {
    int p = atomicAdd(cnt, 1);
    if (p < NCAP) idx[p] = i;
  }
}

// ---------- depth-2 pipelined MFMA K-loop core (3 LDS buffers, counted vmcnt) ----------
// T2 bank-conflict swizzle (proven: SQ_LDS_BANK_CONFLICT 3.1M -> 0): pre-swizzled
// GLOBAL source (ld16 writes linearly) + same-involution swizzled ds_read (rule #21).
#define BK 32

template<int BN>   // 128 (B-tile width) — 256-thread 4-wave form
__device__ __forceinline__ void stage_tile(const unsigned short* A, long long ga0, long long ga1,
                                           const unsigned short* BT, long long gb0, long long gb1,
                                           int k0, unsigned short (*Ab)[BK],
                                           unsigned short (*Bb)[BK], int wave, int sw8) {
  ld16(A + ga0 + k0 + sw8, &Ab[wave * 32][0]);
  ld16(A + ga1 + k0 + sw8, &Ab[wave * 32 + 16][0]);
  ld16(BT + gb0 + k0 + sw8, &Bb[wave * 32][0]);
  ld16(BT + gb1 + k0 + sw8, &Bb[wave * 32 + 16][0]);
}

// ga0/ga1: per-lane global element offsets of this wave's two A sub-rows (row*Kdim),
// computed by caller (supports gathered rows). As: [3*128][BK], Bs: [3*128][BK].
template<int BN>
__device__ __forceinline__ void mfma_pipe(const unsigned short* A, long long ga0, long long ga1,
                                          const unsigned short* BT, int n0, int Kdim,
                                          unsigned short (*As)[BK], unsigned short (*Bs)[BK],
                                          floatx4 (*acc)[BN / 32], int tid) {
  constexpr int NB = BN / 32;               // B fragments per wave
  int wave = tid >> 6, lane = tid & 63;
  int r16 = lane >> 2, c16 = lane & 3;
  int lrow = lane & 15, quad = lane >> 4;
  int wm = (wave & 1) * 64, wn = (wave >> 1) * (BN / 2);
  int NT = Kdim / BK;
  int sw8 = (c16 ^ ((r16 >> 1) & 3)) * 8;   // pre-swizzled global k-chunk (involution)
  int swr = (quad ^ ((lrow >> 1) & 3)) * 8; // swizzled ds_read column
  long long gb0 = (long long)(n0 + wave * 32 + r16) * Kdim;
  long long gb1 = gb0 + 16LL * Kdim;
  // prologue: stage tiles 0 and 1
  stage_tile<BN>(A, ga0, ga1, BT, gb0, gb1, 0, As, Bs, wave, sw8);
  stage_tile<BN>(A, ga0, ga1, BT, gb0, gb1, BK, As + 128, Bs + BN, wave, sw8);
  int cur = 0, nxt = 2;
  for (int t = 0; t < NT; ++t) {
    // drain tile t's loads (own); leave tile t+1's in flight
    if (t == NT - 1) {
      asm volatile("s_waitcnt vmcnt(0)" ::: "memory");
    } else {
      asm volatile("s_waitcnt vmcnt(4)" ::: "memory");
    }
    __builtin_amdgcn_s_barrier();          // all waves' tile-t stages now visible
    if (t + 2 < NT)
      stage_tile<BN>(A, ga0, ga1, BT, gb0, gb1, (t + 2) * BK,
                     As + nxt * 128, Bs + nxt * BN, wave, sw8);
    unsigned short (*Ac)[BK] = As + cur * 128;
    unsigned short (*Bc)[BK] = Bs + cur * BN;
    short8 af[4], bfr[NB];
#pragma unroll
    for (int i = 0; i < 4; ++i) af[i] = *(const short8*)&Ac[wm + i * 16 + lrow][swr];
#pragma unroll
    for (int j = 0; j < NB; ++j) bfr[j] = *(const short8*)&Bc[wn + j * 16 + lrow][swr];
#pragma unroll
    for (int i = 0; i < 4; ++i)
#pragma unroll
      for (int j = 0; j < NB; ++j)
        acc[i][j] = __builtin_amdgcn_mfma_f32_16x16x32_bf16(af[i], bfr[j], acc[i][j], 0, 0, 0);
    cur = (cur == 2) ? 0 : cur + 1;
    nxt = (nxt == 2) ? 0 : nxt + 1;
  }
  __syncthreads();   // protect LDS (union reuse / last-tile reads) before epilogue
}

// ---------- 128x128 MFMA GEMM (linear grid, XCD-swizzled: m0 = bid&63) ----------
// relu->bf16 (FF1)
__global__ __launch_bounds__(256) void mgemm_kernel(const unsigned short* A,
    const unsigned short* BT, long long boff, unsigned short* Cb, int Ndim, int Kdim) {
  __shared__ __align__(16) unsigned short As[3 * 128][BK];
  __shared__ __align__(16) unsigned short Bs[3 * 128][BK];
  int tid = threadIdx.x;
  int bid = blockIdx.x;
  int m0 = (bid & 63) * 128, n0 = (bid >> 6) * 128;
  int wave = tid >> 6, lane = tid & 63;
  int wm = (wave & 1) * 64, wn = (wave >> 1) * 64;
  int lrow = lane & 15, quad = lane >> 4;
  int r16 = lane >> 2;
  floatx4 acc[4][4];
#pragma unroll
  for (int i = 0; i < 4; ++i)
#pragma unroll
    for (int j = 0; j < 4; ++j) acc[i][j] = (floatx4){0.f, 0.f, 0.f, 0.f};
  long long ga0 = (long long)(m0 + wave * 32 + r16) * Kdim;
  long long ga1 = ga0 + 16LL * Kdim;
  mfma_pipe<128>(A, ga0, ga1, BT + boff, n0, Kdim, As, Bs, acc, tid);
#pragma unroll
  for (int i = 0; i < 4; ++i) {
    int mb = m0 + wm + i * 16 + quad * 4;
#pragma unroll
    for (int j = 0; j < 4; ++j) {
      int ncol = n0 + wn + j * 16 + lrow;
#pragma unroll
      for (int r = 0; r < 4; ++r)
        Cb[(long long)(mb + r) * Ndim + ncol] = f2bf(fmaxf(acc[i][j][r], 0.f));
    }
  }
}

// ---------- 128x64 MFMA GEMM — 512 threads / 8 waves (2m x 4n), 4 waves/SIMD ----------
// Doubles per-SIMD wave count vs the 256-thr form so the vmcnt/barrier drain of one
// wave overlaps another wave's ds_read+MFMA. Per wave: acc[4][1], 4 MFMA/iter;
// staging: 1 A ld16/wave (rows wave*16..+16), B ld16 on waves 0-3 only.
// mode: 0 f32 store, 1 f32 add into Cf, 3 +PE f32 store, 4 bf16 store
__global__ __launch_bounds__(512) void mgemm64_kernel(const unsigned short* A,
    const unsigned short* BT, long long boff, float* Cf, unsigned short* Cb,
    int Ndim, int Kdim, int mode) {
  __shared__ __align__(16) unsigned short As[3 * 128][BK];
  __shared__ __align__(16) unsigned short Bs[3 * 64][BK];
  int tid = threadIdx.x;
  int bid = blockIdx.x;
  int m0 = (bid & 63) * 128, n0 = (bid >> 6) * 64;
  int wave = tid >> 6, lane = tid & 63;
  int r16 = lane >> 2, c16 = lane & 3;
  int lrow = lane & 15, quad = lane >> 4;
  int wm = (wave & 1) * 64, wn = (wave >> 1) * 16;
  int sw8 = (c16 ^ ((r16 >> 1) & 3)) * 8;
  int swr = (quad ^ ((lrow >> 1) & 3)) * 8;
  const unsigned short* Bp = BT + boff;
  long long ga = (long long)(m0 + wave * 16 + r16) * Kdim;
  long long gb = (long long)(n0 + (wave & 3) * 16 + r16) * Kdim;
  int hasB = wave < 4;
  floatx4 acc[4];
#pragma unroll
  for (int i = 0; i < 4; ++i) acc[i] = (floatx4){0.f, 0.f, 0.f, 0.f};
  int NT = Kdim / BK;
  // prologue: stage tiles 0 and 1
  ld16(A + ga + sw8, &As[wave * 16][0]);
  if (hasB) ld16(Bp + gb + sw8, &Bs[wave * 16][0]);
  ld16(A + ga + BK + sw8, &As[128 + wave * 16][0]);
  if (hasB) ld16(Bp + gb + BK + sw8, &Bs[64 + wave * 16][0]);
  int cur = 0, nxt = 2;
  for (int t = 0; t < NT; ++t) {
    if (t == NT - 1)  asm volatile("s_waitcnt vmcnt(0)" ::: "memory");
    else if (hasB)    asm volatile("s_waitcnt vmcnt(2)" ::: "memory");
    else              asm volatile("s_waitcnt vmcnt(1)" ::: "memory");
    __builtin_amdgcn_s_barrier();
    if (t + 2 < NT) {
      int k0 = (t + 2) * BK;
      ld16(A + ga + k0 + sw8, &As[nxt * 128 + wave * 16][0]);
      if (hasB) ld16(Bp + gb + k0 + sw8, &Bs[nxt * 64 + wave * 16][0]);
    }
    unsigned short (*Ac)[BK] = As + cur * 128;
    unsigned short (*Bc)[BK] = Bs + cur * 64;
    short8 af[4];
#pragma unroll
    for (int i = 0; i < 4; ++i) af[i] = *(const short8*)&Ac[wm + i * 16 + lrow][swr];
    short8 bfr = *(const short8*)&Bc[wn + lrow][swr];
#pragma unroll
    for (int i = 0; i < 4; ++i)
      acc[i] = __builtin_amdgcn_mfma_f32_16x16x32_bf16(af[i], bfr, acc[i], 0, 0, 0);
    cur = (cur == 2) ? 0 : cur + 1;
    nxt = (nxt == 2) ? 0 : nxt + 1;
  }
#pragma unroll
  for (int i = 0; i < 4; ++i) {
    int mb = m0 + wm + i * 16 + quad * 4;
    int ncol = n0 + wn + lrow;
#pragma unroll
    for (int r = 0; r < 4; ++r) {
      int m = mb + r;
      long long idx = (long long)m * Ndim + ncol;
      float v = acc[i][r];
      if (mode == 1) Cf[idx] += v;
      else if (mode == 4) Cb[idx] = f2bf(v);
      else if (mode == 3) {
        int t = m & (T_ - 1);
        float freq = __expf(-(float)(ncol & ~1) * (9.210340371976184f / (float)D_));
        float ang = (float)t * freq;
        v += (ncol & 1) ? cosf(ang) : sinf(ang);
        Cf[idx] = v;
      } else Cf[idx] = v;
    }
  }
}

// ---------- QKV GEMM: Q direct; K/V via LDS transpose -> coalesced tile stores ----------
__global__ __launch_bounds__(256) void qkvgemm_kernel(const unsigned short* A,
    const unsigned short* BT, long long boff, unsigned short* QB,
    unsigned short* KSg, unsigned short* VTSg) {
  __shared__ __align__(16) union {
    struct { unsigned short As[3 * 128][BK]; unsigned short Bs[3 * 128][BK]; } s;
    unsigned short T[128][136];
  } sm;
  int tid = threadIdx.x;
  int bid = blockIdx.x;
  int m0 = (bid & 63) * 128;
  int nt = bid >> 6;
  int n0 = nt * 128;
  int wave = tid >> 6, lane = tid & 63;
  int wm = (wave & 1) * 64, wn = (wave >> 1) * 64;
  int lrow = lane & 15, quad = lane >> 4;
  int r16 = lane >> 2;
  floatx4 acc[4][4];
#pragma unroll
  for (int i = 0; i < 4; ++i)
#pragma unroll
    for (int j = 0; j < 4; ++j) acc[i][j] = (floatx4){0.f, 0.f, 0.f, 0.f};
  long long ga0 = (long long)(m0 + wave * 32 + r16) * D_;
  long long ga1 = ga0 + 16LL * D_;
  mfma_pipe<128>(A, ga0, ga1, BT + boff, n0, D_, sm.s.As, sm.s.Bs, acc, tid);
  int b = m0 >> 10, tt = (m0 >> 7) & 7;
  if (nt < 4) {
#pragma unroll
    for (int i = 0; i < 4; ++i) {
      int mb = m0 + wm + i * 16 + quad * 4;
#pragma unroll
      for (int j = 0; j < 4; ++j) {
        int ncol = n0 + wn + j * 16 + lrow;
#pragma unroll
        for (int r = 0; r < 4; ++r)
          QB[(long long)(mb + r) * 512 + ncol] = f2bf(acc[i][j][r]);
      }
    }
  } else if (nt < 8) {
#pragma unroll
    for (int i = 0; i < 4; ++i)
#pragma unroll
      for (int j = 0; j < 4; ++j)
#pragma unroll
        for (int r = 0; r < 4; ++r)
          sm.T[wm + i * 16 + quad * 4 + r][wn + j * 16 + lrow] = f2bf(acc[i][j][r]);
    __syncthreads();
    int tk = tid & 127, hg0 = tid >> 7;
#pragma unroll
    for (int p = 0; p < 8; ++p) {
      int hg = p * 2 + hg0;
      int h2 = hg >> 3, g = hg & 7;
      uint4 u = *(const uint4*)&sm.T[tk][h2 * 64 + g * 8];
      int headg = (nt - 4) * 2 + h2;
      long long dst = (((((long long)(b * 8 + headg)) * 8 + tt) * 8 + g) * 128 + tk) * 8;
      *(uint4*)&KSg[dst] = u;
    }
  } else {
#pragma unroll
    for (int i = 0; i < 4; ++i)
#pragma unroll
      for (int j = 0; j < 4; ++j)
#pragma unroll
        for (int r = 0; r < 4; ++r)
          sm.T[wn + j * 16 + lrow][wm + i * 16 + quad * 4 + r] = f2bf(acc[i][j][r]);
    __syncthreads();
    int col = tid & 127, gh = tid >> 7;
    int h2 = col >> 6, ch = col & 63;
    int headg = (nt - 8) * 2 + h2;
    long long base = ((((long long)(b * 8 + headg)) * 8 + tt) * 16);
#pragma unroll
    for (int p = 0; p < 8; ++p) {
      int g = p * 2 + gh;
      uint4 u = *(const uint4*)&sm.T[col][g * 8];
      long long dst = ((base + g) * 64 + ch) * 8;
      *(uint4*)&VTSg[dst] = u;
    }
  }
}

// ---------- flash MFMA attention: barrier-free, early-issue load schedule ----------
// Round-2 structure with load issue points hoisted so every global load has a
// VALU/MFMA phase covering its latency (T14). Proven: fattn <46us.
__global__ __launch_bounds__(256) void fattn_kernel(const unsigned short* QB,
    const unsigned short* KSg, const unsigned short* VTSg, const int* lens,
    unsigned short* ao) {
  __shared__ __align__(16) unsigned short Ps[64 * 128];
  int blk = blockIdx.x;                     // 1024 blocks = 16 qt x 64 bh
  int swz = (blk & 7) * 128 + (blk >> 3);   // XCD-contiguous: 128 logical blocks/XCD
  int qt = swz & 15, bh = swz >> 4;
  int b = bh >> 3, h = bh & 7;
  int tid = threadIdx.x, wave = tid >> 6, lane = tid & 63;
  int c = lane & 15, quad = lane >> 4;
  int len = lens[b];
  short8 qf[2];
#pragma unroll
  for (int ks = 0; ks < 2; ++ks)
    qf[ks] = *(const short8*)&QB[(long long)(b * 1024 + qt * 64 + wave * 16 + c) * 512
                                 + h * 64 + ks * 32 + quad * 8];
  floatx4 accO[4];
  float lr[4];
#pragma unroll
  for (int j = 0; j < 4; ++j) { accO[j] = (floatx4){0.f, 0.f, 0.f, 0.f}; lr[j] = 0.f; }
  int nkt = (len + 127) >> 7;
  const unsigned short* kp = KSg + (long long)bh * 65536;
  const unsigned short* vp = VTSg + (long long)bh * 65536;
  int kb = (quad * 128 + c) * 8;            // K frag base; +j*128 per j, +4096 for hb=1
  int vbase = quad * 512 + c * 8;           // V frag base; +X*2048 +jn*128
  int row = wave * 16 + c;
  short8 kA[8], kB[8], vA[8], vB[8];
  // preload K(kt=0) jh0 -> kA
#pragma unroll
  for (int j2 = 0; j2 < 4; ++j2) {
    kA[j2]     = *(const short8*)&kp[kb + j2 * 128];
    kA[4 + j2] = *(const short8*)&kp[kb + 4096 + j2 * 128];
  }
  for (int kt = 0; kt < nkt; ++kt) {
    int kbase = kt * 128;
    const unsigned short* kpc = kp + kt * 8192;
    const unsigned short* vpc = vp + kt * 8192;
    const unsigned short* kpn = kpc + 8192;
    int more = (kt + 1 < nkt);
    // issue K jh1 -> kB (covered by QK jh0 + softmax jh0)
#pragma unroll
    for (int j2 = 0; j2 < 4; ++j2) {
      kB[j2]     = *(const short8*)&kpc[kb + (4 + j2) * 128];
      kB[4 + j2] = *(const short8*)&kpc[kb + 4096 + (4 + j2) * 128];
    }
    // ---- QK jh0 (kA) ----
    floatx4 s0[4];
#pragma unroll
    for (int j2 = 0; j2 < 4; ++j2) s0[j2] = (floatx4){0.f, 0.f, 0.f, 0.f};
#pragma unroll
    for (int j2 = 0; j2 < 4; ++j2) {
      s0[j2] = __builtin_amdgcn_mfma_f32_16x16x32_bf16(qf[0], kA[j2], s0[j2], 0, 0, 0);
      s0[j2] = __builtin_amdgcn_mfma_f32_16x16x32_bf16(qf[1], kA[4 + j2], s0[j2], 0, 0, 0);
    }
    // issue V kh0 -> vA (covered by softmax jh0 + QK jh1)
#pragma unroll
    for (int q = 0; q < 8; ++q)
      vA[q] = *(const short8*)&vpc[(q >> 2) * 2048 + (q & 3) * 128 + vbase];
    // softmax jh0 -> Ps cols 0..63
#pragma unroll
    for (int r = 0; r < 4; ++r) {
      int prow = wave * 16 + quad * 4 + r;
      int rx = quad * 4 + r;
#pragma unroll
      for (int j2 = 0; j2 < 4; ++j2) {
        int col = j2 * 16 + c;
        float s = s0[j2][r] * 0.125f;
        s = (kbase + col < len) ? s : -100.f;
        float p = __expf(s);
        lr[r] += p;
        Ps[prow * 128 + (((col >> 3) ^ rx) * 8) + (col & 7)] = f2bf(p);
      }
    }
    // ---- QK jh1 (kB) ----
    floatx4 s1[4];
#pragma unroll
    for (int j2 = 0; j2 < 4; ++j2) s1[j2] = (floatx4){0.f, 0.f, 0.f, 0.f};
#pragma unroll
    for (int j2 = 0; j2 < 4; ++j2) {
      s1[j2] = __builtin_amdgcn_mfma_f32_16x16x32_bf16(qf[0], kB[j2], s1[j2], 0, 0, 0);
      s1[j2] = __builtin_amdgcn_mfma_f32_16x16x32_bf16(qf[1], kB[4 + j2], s1[j2], 0, 0, 0);
    }
    // issue V kh1 -> vB (covered by softmax jh1)
#pragma unroll
    for (int q = 0; q < 8; ++q)
      vB[q] = *(const short8*)&vpc[(2 + (q >> 2)) * 2048 + (q & 3) * 128 + vbase];
    // softmax jh1 -> Ps cols 64..127
#pragma unroll
    for (int r = 0; r < 4; ++r) {
      int prow = wave * 16 + quad * 4 + r;
      int rx = quad * 4 + r;
#pragma unroll
      for (int j2 = 0; j2 < 4; ++j2) {
        int col = (4 + j2) * 16 + c;
        float s = s1[j2][r] * 0.125f;
        s = (kbase + col < len) ? s : -100.f;
        float p = __expf(s);
        lr[r] += p;
        Ps[prow * 128 + (((col >> 3) ^ rx) * 8) + (col & 7)] = f2bf(p);
      }
    }
    // ---- PV kh0 (vA) ----
#pragma unroll
    for (int kk2 = 0; kk2 < 2; ++kk2) {
      short8 pa = *(const short8*)&Ps[row * 128 + (((kk2 * 4 + quad) ^ c) * 8)];
#pragma unroll
      for (int jn = 0; jn < 4; ++jn)
        accO[jn] = __builtin_amdgcn_mfma_f32_16x16x32_bf16(pa, vA[kk2 * 4 + jn], accO[jn], 0, 0, 0);
    }
    // issue next K jh0 -> kA (vA dead; covered by PV kh1)
    if (more) {
#pragma unroll
      for (int j2 = 0; j2 < 4; ++j2) {
        kA[j2]     = *(const short8*)&kpn[kb + j2 * 128];
        kA[4 + j2] = *(const short8*)&kpn[kb + 4096 + j2 * 128];
      }
    }
    // ---- PV kh1 (vB) ----
#pragma unroll
    for (int kk2 = 0; kk2 < 2; ++kk2) {
      int kk = 2 + kk2;
      short8 pa = *(const short8*)&Ps[row * 128 + (((kk * 4 + quad) ^ c) * 8)];
#pragma unroll
      for (int jn = 0; jn < 4; ++jn)
        accO[jn] = __builtin_amdgcn_mfma_f32_16x16x32_bf16(pa, vB[kk2 * 4 + jn], accO[jn], 0, 0, 0);
    }
  }
  // deferred row-reduce, normalize + store
#pragma unroll
  for (int r = 0; r < 4; ++r) {
    float ls = lr[r];
    ls += __shfl_xor(ls, 1, 64);
    ls += __shfl_xor(ls, 2, 64);
    ls += __shfl_xor(ls, 4, 64);
    ls += __shfl_xor(ls, 8, 64);
    float inv = 1.f / ls;
    long long token = b * 1024 + qt * 64 + wave * 16 + quad * 4 + r;
#pragma unroll
    for (int jn = 0; jn < 4; ++jn)
      ao[token * 512 + h * 64 + jn * 16 + c] = f2bf(accO[jn][r] * inv);
  }
}

// ---------- argmin GEMM over COMPACTED rows: dist = enorm[v] - 2*(Z[idx].ET^T) ----------
__global__ __launch_bounds__(256) void dgemm_argmin(const unsigned short* Z, const int* ridx,
    const int* cnt, const unsigned short* ET, const float* en, unsigned long long* best) {
  __shared__ __align__(16) union {
    struct { unsigned short A[3 * 128][BK]; unsigned short B[3 * 128][BK]; } s;
    unsigned long long part[128][33];
  } sm;
  int m0 = blockIdx.y * 128;
  int na = *cnt;
  if (m0 >= ((na + 127) & ~127)) return;
  int tid = threadIdx.x;
  int n0 = blockIdx.x * 128;
  int wave = tid >> 6, lane = tid & 63;
  int wm = (wave & 1) * 64, wn = (wave >> 1) * 64;
  int lrow = lane & 15, quad = lane >> 4;
  int r16 = lane >> 2;
  int slot = (wave >> 1) * 16 + lrow;
  floatx4 acc[4][4];
#pragma unroll
  for (int i = 0; i < 4; ++i)
#pragma unroll
    for (int j = 0; j < 4; ++j) acc[i][j] = (floatx4){0.f, 0.f, 0.f, 0.f};
  long long ga0 = (long long)ridx[m0 + wave * 32 + r16] * D_;
  long long ga1 = (long long)ridx[m0 + wave * 32 + 16 + r16] * D_;
  mfma_pipe<128>(Z, ga0, ga1, ET, n0, D_, sm.s.A, sm.s.B, acc, tid);
  float env[4];
#pragma unroll
  for (int j = 0; j < 4; ++j) env[j] = en[n0 + wn + j * 16 + lrow];
#pragma unroll
  for (int i = 0; i < 4; ++i) {
#pragma unroll
    for (int r = 0; r < 4; ++r) {
      int rowl = wm + i * 16 + quad * 4 + r;
      unsigned long long bl = ~0ull;
#pragma unroll
      for (int j = 0; j < 4; ++j) {
        float v = env[j] - 2.f * acc[i][j][r];
        unsigned long long pk = (((unsigned long long)fkey(v)) << 32) |
                                (unsigned int)(n0 + wn + j * 16 + lrow);
        if (pk < bl) bl = pk;
      }
      sm.part[rowl][(slot + rowl) & 31] = bl;
    }
  }
  __syncthreads();
  if (tid < 128) {
    unsigned long long bb = sm.part[tid][0];
#pragma unroll 4
    for (int k2 = 1; k2 < 32; ++k2) { unsigned long long o = sm.part[tid][k2]; if (o < bb) bb = o; }
    atomicMin(&best[m0 + tid], bb);
  }
}

// ---------- logits GEMM over COMPACTED rows: fixed-offset LSE + target logit ----------
__global__ __launch_bounds__(256) void lgemm_lse(const unsigned short* OUTB, const int* ridx,
    const int* cnt, const unsigned short* TOPT, const unsigned long long* best,
    float* PS, float* TL) {
  __shared__ __align__(16) union {
    struct { unsigned short A[3 * 128][BK]; unsigned short B[3 * 128][BK]; } s;
    float part[128][33];
  } sm;
  int m0 = blockIdx.y * 128;
  int na = *cnt;
  if (m0 >= ((na + 127) & ~127)) return;
  int tid = threadIdx.x;
  int n0 = blockIdx.x * 128;
  int wave = tid >> 6, lane = tid & 63;
  int wm = (wave & 1) * 64, wn = (wave >> 1) * 64;
  int lrow = lane & 15, quad = lane >> 4;
  int r16 = lane >> 2;
  int slot = (wave >> 1) * 16 + lrow;
  floatx4 acc[4][4];
#pragma unroll
  for (int i = 0; i < 4; ++i)
#pragma unroll
    for (int j = 0; j < 4; ++j) acc[i][j] = (floatx4){0.f, 0.f, 0.f, 0.f};
  long long ga0 = (long long)ridx[m0 + wave * 32 + r16] * D_;
  long long ga1 = (long long)ridx[m0 + wave * 32 + 16 + r16] * D_;
  mfma_pipe<128>(OUTB, ga0, ga1, TOPT, n0, D_, sm.s.A, sm.s.B, acc, tid);
#pragma unroll
  for (int i = 0; i < 4; ++i) {
#pragma unroll
    for (int r = 0; r < 4; ++r) {
      int rowl = wm + i * 16 + quad * 4 + r;
      int tg = (int)(best[m0 + rowl] & 0xffffffffu);
      float ss = 0.f;
#pragma unroll
      for (int j = 0; j < 4; ++j) {
        float v = acc[i][j][r];
        ss += __expf(v);
        if (n0 + wn + j * 16 + lrow == tg) TL[m0 + rowl] = v;
      }
      sm.part[rowl][(slot + rowl) & 31] = ss;
    }
  }
  __syncthreads();
  if (tid < 128) {
    float S = 0.f;
#pragma unroll 4
    for (int k2 = 0; k2 < 32; ++k2) S += sm.part[tid][k2];
    PS[(long long)(m0 + tid) * 64 + blockIdx.x] = S;
  }
}

__global__ void lse_combine(const float* PS, const float* TL, const int* cnt, float* entm) {
  int t = blockIdx.x * 256 + threadIdx.x;   // compact index, grid covers NCAP
  if (t >= NCAP) return;
  if (t < *cnt) {
    float S = 0.f;
    for (int i = 0; i < 64; ++i) S += PS[(long long)t * 64 + i];
    entm[t] = __logf(S) - TL[t];            // mcomb == 1 for active rows
  } else {
    entm[t] = 0.f;
  }
}

// ---------- layernorm: wave per token, shuffle reductions ----------
__global__ __launch_bounds__(256) void ln_kernel(const float* X, float* Yf, unsigned short* Yb,
                                                 int obf, const float* s, const float* b) {
  int tid = threadIdx.x, wave = tid >> 6, lane = tid & 63;
  long long n = (long long)blockIdx.x * 4 + wave;
  const float* x = X + n * D_ + lane * 8;
  float v[8];
  *(float4*)&v[0] = *(const float4*)x;
  *(float4*)&v[4] = *(const float4*)(x + 4);
  float sum = 0.f;
#pragma unroll
  for (int j = 0; j < 8; ++j) sum += v[j];
  for (int m = 32; m; m >>= 1) sum += __shfl_xor(sum, m, 64);
  float mean = sum * (1.f / (float)D_);
  float vs = 0.f;
#pragma unroll
  for (int j = 0; j < 8; ++j) { v[j] -= mean; vs += v[j] * v[j]; }
  for (int m = 32; m; m >>= 1) vs += __shfl_xor(vs, m, 64);
  float r = rsqrtf(vs * (1.f / (float)D_) + EPS_);
  float sv[8], bv[8];
  *(float4*)&sv[0] = *(const float4*)(s + lane * 8);
  *(float4*)&sv[4] = *(const float4*)(s + lane * 8 + 4);
  *(float4*)&bv[0] = *(const float4*)(b + lane * 8);
  *(float4*)&bv[4] = *(const float4*)(b + lane * 8 + 4);
  if (obf) {
    unsigned short o[8];
#pragma unroll
    for (int j = 0; j < 8; ++j) o[j] = f2bf(v[j] * r * sv[j] + bv[j]);
    *(uint4*)(Yb + n * D_ + lane * 8) = *(const uint4*)o;
  } else {
    float o[8];
#pragma unroll
    for (int j = 0; j < 8; ++j) o[j] = v[j] * r * sv[j] + bv[j];
    *(float4*)(Yf + n * D_ + lane * 8) = *(const float4*)&o[0];
    *(float4*)(Yf + n * D_ + lane * 8 + 4) = *(const float4*)&o[4];
  }
}

// ---------- masked_xs ----------
__global__ void maskapply_kernel(float* x, const int* maski, const float* memb) {
  long long i = (long long)blockIdx.x * 256 + threadIdx.x;
  int n = (int)(i >> 9), d = (int)(i & 511);
  if (maski[n]) x[i] = memb[d];
}

// ---------- final reduce + dual-dtype write ----------
__global__ void final_kernel(const float* entm, const float* mcomb, void* out) {
  __shared__ float r1[256], r2[256];
  int tid = threadIdx.x;
  float s1 = 0.f, s2 = 0.f;
  for (int i = tid; i < NCAP; i += 256) s1 += entm[i];
  for (int i = tid; i < NTOK; i += 256) s2 += mcomb[i];
  r1[tid] = s1; r2[tid] = s2;
  __syncthreads();
  for (int st = 128; st > 0; st >>= 1) {
    if (tid < st) { r1[tid] += r1[tid + st]; r2[tid] += r2[tid + st]; }
    __syncthreads();
  }
  if (tid == 0) {
    float loss = r1[0] / r2[0];
    unsigned short b16 = f2bf(loss);
    unsigned short* o = (unsigned short*)out;
    o[0] = b16; o[1] = b16;
  }
}

extern "C" void kernel_launch(void* const* d_in, const int* in_sizes, int n_in,
                              void* d_out, int out_size, void* d_ws, size_t ws_size,
                              hipStream_t stream) {
  if (n_in < 20) return;
  float* wsf = (float*)d_ws;
  int* flags = (int*)d_ws;
  const long long OF_P = 256;
  const long long OF_X = 16640;
  const long long OF_HB = OF_X + 4194304;
  const long long OF_BIG = OF_HB + 2097152;
  const long long OF_AOB = OF_BIG + 8388608;
  const long long OF_WT = OF_AOB + 2097152;
  const long long OF_TOPT = OF_WT + 9699328;
  const long long OF_EMBT = OF_TOPT + 2097152;
  const long long OF_EN = OF_EMBT + 2097152;
  const long long OF_BEST = OF_EN + 8192;          // NCAP u64 = 4096 floats
  const long long OF_PS = OF_BEST + 4096;          // NCAP*64 floats
  const long long OF_TL = OF_PS + 131072;          // NCAP
  const long long OF_MI = OF_TL + 2048;
  const long long OF_MC = OF_MI + 8192;
  const long long OF_EM = OF_MC + 8192;            // NCAP
  const long long OF_CNT = OF_EM + 2048;
  const long long OF_IDX = OF_CNT + 16;            // NCAP ints
  const long long END = OF_IDX + 2048;
  if (ws_size < (size_t)END * 4) return;

  float* X = wsf + OF_X;
  unsigned short* HB = (unsigned short*)(wsf + OF_HB);
  unsigned short* BIGB = (unsigned short*)(wsf + OF_BIG);
  unsigned short* AOB = (unsigned short*)(wsf + OF_AOB);
  unsigned short* WT = (unsigned short*)(wsf + OF_WT);
  unsigned short* TOPT = (unsigned short*)(wsf + OF_TOPT);
  unsigned short* EMBT = (unsigned short*)(wsf + OF_EMBT);
  float* EN = wsf + OF_EN;
  unsigned long long* BEST = (unsigned long long*)(wsf + OF_BEST);
  float* PS = wsf + OF_PS;
  float* TL = wsf + OF_TL;
  int* MI = (int*)(wsf + OF_MI);
  float* MC = wsf + OF_MC;
  float* EM = wsf + OF_EM;
  int* CNT = (int*)(wsf + OF_CNT);
  int* IDX = (int*)(wsf + OF_IDX);
  float* P = wsf + OF_P;
  float* ln1s = P, *ln1b = P + 3072, *ln2s = P + 6144, *ln2b = P + 9216;
  float* ans = P + 12288, *anb = P + 12800, *ilns = P + 13312, *ilnb = P + 13824;
  float* memb = P + 14336;

  unsigned short* QB = BIGB;
  unsigned short* KSg = BIGB + 4194304;
  unsigned short* VTSg = BIGB + 8388608;

  const long long W_QKV = 0, W_O = 4718592, W_1 = 6291456, W_2 = 12582912,
                  W_EMB = 18874368, W_PRJ = 19136512;

  detect_kernel<<<1, 256, 0, stream>>>((const unsigned int*)d_in[0],
                                       (const unsigned int*)d_in[2], flags);
  hipMemsetAsync((void*)BEST, 0xFF, NCAP * 8, stream);
  hipMemsetAsync((void*)EN, 0, V_ * 4, stream);
  hipMemsetAsync((void*)CNT, 0, 16, stream);
  hipMemsetAsync((void*)IDX, 0, NCAP * 4, stream);
  conv_all_kernel<<<58, 256, 0, stream>>>(d_in[4], d_in[5], d_in[8], d_in[9], d_in[12],
                                          d_in[13], d_in[14], d_in[15], d_in[16], P, flags);
  prep_kernel<<<32, 256, 0, stream>>>(d_in[2], (const int*)d_in[1], MI, MC, IDX, CNT, flags);

  unsigned short* XSB = BIGB;
  convb_kernel<<<16384, 256, 0, stream>>>(d_in[0], XSB, 4194304, flags);

  trans_kernel<<<dim3(48, 16, 6), 256, 0, stream>>>(d_in[6], WT + W_QKV, 512, 1536, flags);
  trans_kernel<<<dim3(16, 16, 6), 256, 0, stream>>>(d_in[7], WT + W_O, 512, 512, flags);
  trans_kernel<<<dim3(64, 16, 6), 256, 0, stream>>>(d_in[10], WT + W_1, 512, 2048, flags);
  trans_kernel<<<dim3(16, 64, 6), 256, 0, stream>>>(d_in[11], WT + W_2, 2048, 512, flags);
  trans_kernel<<<dim3(16, 16, 1), 256, 0, stream>>>(d_in[3], WT + W_EMB, 512, 512, flags);
  trans_kernel<<<dim3(16, 16, 1), 256, 0, stream>>>(d_in[18], WT + W_PRJ, 512, 512, flags);
  trans_big_kernel<<<dim3(256, 16, 2), 256, 0, stream>>>(d_in[17], d_in[19], TOPT, EMBT,
                                                         EN, flags);

  dim3 gC(64, NCAP / 128);   // compacted V-GEMMs: 16 row-tiles, device-side early exit

  // x = xs @ W_embed + PE
  mgemm64_kernel<<<512, 512, 0, stream>>>(XSB, WT + W_EMB, 0, X, nullptr, 512, 512, 3);
  // target ids (needed only for masked&padded tokens -> compacted)
  ln_kernel<<<2048, 256, 0, stream>>>(X, nullptr, HB, 1, ilns, ilnb);
  mgemm64_kernel<<<512, 512, 0, stream>>>(HB, WT + W_PRJ, 0, nullptr, AOB, 512, 512, 4);
  dgemm_argmin<<<gC, 256, 0, stream>>>(AOB, IDX, CNT, EMBT, EN, BEST);
  maskapply_kernel<<<16384, 256, 0, stream>>>(X, MI, memb);

  for (int l = 0; l < L_; ++l) {
    ln_kernel<<<2048, 256, 0, stream>>>(X, nullptr, HB, 1, ln1s + l * 512, ln1b + l * 512);
    qkvgemm_kernel<<<768, 256, 0, stream>>>(HB, WT + W_QKV, (long long)l * 786432,
                                            QB, KSg, VTSg);
    fattn_kernel<<<1024, 256, 0, stream>>>(QB, KSg, VTSg, (const int*)d_in[1], AOB);
    mgemm64_kernel<<<512, 512, 0, stream>>>(AOB, WT + W_O, (long long)l * 262144,
                                            X, nullptr, 512, 512, 1);
    ln_kernel<<<2048, 256, 0, stream>>>(X, nullptr, HB, 1, ln2s + l * 512, ln2b + l * 512);
    mgemm_kernel<<<1024, 256, 0, stream>>>(HB, WT + W_1, (long long)l * 1048576,
                                           BIGB, 2048, 512);
    mgemm64_kernel<<<512, 512, 0, stream>>>(BIGB, WT + W_2, (long long)l * 1048576,
                                            X, nullptr, 512, 2048, 1);
  }
  ln_kernel<<<2048, 256, 0, stream>>>(X, nullptr, AOB, 1, ans, anb);
  lgemm_lse<<<gC, 256, 0, stream>>>(AOB, IDX, CNT, TOPT, BEST, PS, TL);
  lse_combine<<<8, 256, 0, stream>>>(PS, TL, CNT, EM);
  final_kernel<<<1, 256, 0, stream>>>(EM, MC, d_out);
}

// Round 8
// 1201.057 us; speedup vs baseline: 1.1506x; 1.0212x over previous
//
#include <hip/hip_runtime.h>
#include <hip/hip_bf16.h>

#define D_ 512
#define T_ 1024
#define B_ 8
#define H_ 8
#define F_ 2048
#define V_ 8192
#define L_ 6
#define NTOK 8192
#define EPS_ 1e-5f
#define NCAP 2048   // compacted-row capacity (E[NA]~737, +52 sigma)

typedef short short8 __attribute__((ext_vector_type(8)));
typedef float floatx4 __attribute__((ext_vector_type(4)));

__device__ __forceinline__ float bf2f(unsigned short u) {
  union { unsigned int i; float f; } v; v.i = ((unsigned int)u) << 16; return v.f;
}
__device__ __forceinline__ unsigned short f2bf(float f) {
  unsigned int u = __float_as_uint(f);
  return (unsigned short)((u + 0x7fffu + ((u >> 16) & 1u)) >> 16);
}
__device__ __forceinline__ float ldf(const void* p, long long i, int bf) {
  if (bf) return bf2f(((const unsigned short*)p)[i]);
  return ((const float*)p)[i];
}
// async global->LDS, 16B per lane; LDS dest = wave-uniform base + lane*16 (global addr per-lane OK)
__device__ __forceinline__ void ld16(const unsigned short* g, unsigned short* l) {
  __builtin_amdgcn_global_load_lds(
      (const __attribute__((address_space(1))) unsigned int*)g,
      (__attribute__((address_space(3))) unsigned int*)l, 16, 0, 0);
}
__device__ __forceinline__ unsigned int fkey(float f) {
  unsigned int u = __float_as_uint(f);
  return (u & 0x80000000u) ? ~u : (u ^ 0x80000000u);
}

// ---------- dtype detection (flags[0]: inputs bf16?, flags[1]: mask fmt) ----------
__global__ void detect_kernel(const unsigned int* xsw, const unsigned int* mw, int* flags) {
  __shared__ int cnt[256];
  __shared__ int m01[256], mlo[256], mhi[256];
  int tid = threadIdx.x;
  int c = 0;
  for (int t = tid; t < 1024; t += 256) {
    unsigned int lo = xsw[t] & 0xffffu;
    int ok;
    if (lo == 0u) ok = 1;
    else { unsigned int e = (lo >> 7) & 0xffu; ok = (e >= 90u && e <= 140u); }
    c += ok;
  }
  int n01 = 0, lo38 = 0, hi38 = 0;
  for (int t = tid; t < 2048; t += 256) {
    unsigned int w = mw[t];
    if (w > 1u) n01 = 1;
    if ((w & 0xffffu) == 0x3f80u) lo38 = 1;
    if ((w >> 16) == 0x3f80u) hi38 = 1;
  }
  cnt[tid] = c; m01[tid] = n01; mlo[tid] = lo38; mhi[tid] = hi38;
  __syncthreads();
  for (int s = 128; s > 0; s >>= 1) {
    if (tid < s) {
      cnt[tid] += cnt[tid + s];
      m01[tid] |= m01[tid + s]; mlo[tid] |= mlo[tid + s]; mhi[tid] |= mhi[tid + s];
    }
    __syncthreads();
  }
  if (tid == 0) {
    flags[0] = (cnt[0] > 700) ? 1 : 0;
    int fmt;
    if (!m01[0]) fmt = 0;
    else if (mlo[0]) fmt = 2;
    else if (mhi[0]) fmt = 3;
    else fmt = 1;
    flags[1] = fmt;
  }
}

// ---------- all small param vectors -> f32 P block (one launch) ----------
__global__ void conv_all_kernel(const void* d4, const void* d5, const void* d8,
                                const void* d9, const void* d12, const void* d13,
                                const void* d14, const void* d15, const void* d16,
                                float* P, const int* flags) {
  int i = blockIdx.x * 256 + threadIdx.x;
  if (i >= 14848) return;
  int bf = flags[0];
  const void* src; int off;
  if (i < 3072) { src = d4; off = 0; }
  else if (i < 6144) { src = d5; off = 3072; }
  else if (i < 9216) { src = d8; off = 6144; }
  else if (i < 12288) { src = d9; off = 9216; }
  else if (i < 12800) { src = d12; off = 12288; }
  else if (i < 13312) { src = d13; off = 12800; }
  else if (i < 13824) { src = d14; off = 13312; }
  else if (i < 14336) { src = d15; off = 13824; }
  else { src = d16; off = 14336; }
  P[i] = ldf(src, i - off, bf);
}

__global__ void convb_kernel(const void* src, unsigned short* dst, int n, const int* flags) {
  int i = blockIdx.x * 256 + threadIdx.x;
  if (i < n) {
    if (flags[0]) dst[i] = ((const unsigned short*)src)[i];
    else dst[i] = f2bf(((const float*)src)[i]);
  }
}

// ---------- weight convert + transpose: src [batch][K][N] -> dst [batch][N][K] bf16 ----------
__global__ __launch_bounds__(256) void trans_kernel(const void* src, unsigned short* dst,
                                                    int K, int N, const int* flags) {
  int bf = flags[0];
  __shared__ unsigned short tile[32][33];
  int n0 = blockIdx.x * 32, k0 = blockIdx.y * 32, batch = blockIdx.z;
  long long sbase = (long long)batch * K * N;
  long long dbase = (long long)batch * N * K;
  int c = threadIdx.x & 31, r8 = threadIdx.x >> 5;
#pragma unroll
  for (int rr = 0; rr < 4; ++rr) {
    int r = r8 + rr * 8;
    tile[r][c] = f2bf(ldf(src, sbase + (long long)(k0 + r) * N + n0 + c, bf));
  }
  __syncthreads();
#pragma unroll
  for (int rr = 0; rr < 4; ++rr) {
    int nn = r8 + rr * 8;
    dst[dbase + (long long)(n0 + nn) * K + k0 + c] = tile[c][nn];
  }
}

// ---------- big [512][8192] transposes (TOPT z=0, EMBT z=1) + fused enorm ----------
__global__ __launch_bounds__(256) void trans_big_kernel(const void* top, const void* emb,
                                                        unsigned short* TOPT, unsigned short* EMBT,
                                                        float* en, const int* flags) {
  int bf = flags[0];
  __shared__ unsigned short tile[32][33];
  int n0 = blockIdx.x * 32, k0 = blockIdx.y * 32, z = blockIdx.z;
  const void* src = z ? emb : top;
  unsigned short* dst = z ? EMBT : TOPT;
  int c = threadIdx.x & 31, r8 = threadIdx.x >> 5;
#pragma unroll
  for (int rr = 0; rr < 4; ++rr) {
    int r = r8 + rr * 8;
    tile[r][c] = f2bf(ldf(src, (long long)(k0 + r) * V_ + n0 + c, bf));
  }
  __syncthreads();
#pragma unroll
  for (int rr = 0; rr < 4; ++rr) {
    int nn = r8 + rr * 8;
    dst[(long long)(n0 + nn) * D_ + k0 + c] = tile[c][nn];
  }
  if (z == 1 && threadIdx.x < 32) {
    int nn = threadIdx.x;
    float s = 0.f;
#pragma unroll
    for (int r = 0; r < 32; ++r) { float x = bf2f(tile[r][nn]); s += x * x; }
    atomicAdd(&en[n0 + nn], s);
  }
}

// ---------- mask / pad prep + active-token compaction ----------
__global__ void prep_kernel(const void* mask, const int* lens, int* maski, float* mcomb,
                            int* idx, int* cnt, const int* flags) {
  int i = blockIdx.x * 256 + threadIdx.x;
  if (i >= NTOK) return;
  int fmt = flags[1];
  int mi;
  if (fmt == 0) mi = ((const int*)mask)[i] != 0;
  else if (fmt == 1) mi = ((const unsigned char*)mask)[i] != 0;
  else if (fmt == 2) mi = ((const unsigned short*)mask)[i] != 0;
  else mi = ((const float*)mask)[i] != 0.f;
  int b = i >> 10, t = i & (T_ - 1);
  int act = mi && (t < lens[b]);
  maski[i] = mi;
  mcomb[i] = act ? 1.f : 0.f;
  if (act) {
    int p = atomicAdd(cnt, 1);
    if (p < NCAP) idx[p] = i;
  }
}

// ---------- depth-2 pipelined MFMA K-loop cores (3 LDS buffers, counted vmcnt) ----------
// T2 bank-conflict swizzle (proven: SQ_LDS_BANK_CONFLICT 3.1M -> 0): pre-swizzled
// GLOBAL source (ld16 writes linearly) + same-involution swizzled ds_read (rule #21).
#define BK 32

// ---- 4-wave (256-thread) form, used by dgemm_argmin / lgemm_lse (gathered A rows) ----
template<int BN>
__device__ __forceinline__ void stage_tile(const unsigned short* A, long long ga0, long long ga1,
                                           const unsigned short* BT, long long gb0, long long gb1,
                                           int k0, unsigned short (*Ab)[BK],
                                           unsigned short (*Bb)[BK], int wave, int sw8) {
  ld16(A + ga0 + k0 + sw8, &Ab[wave * 32][0]);
  ld16(A + ga1 + k0 + sw8, &Ab[wave * 32 + 16][0]);
  ld16(BT + gb0 + k0 + sw8, &Bb[wave * 32][0]);
  ld16(BT + gb1 + k0 + sw8, &Bb[wave * 32 + 16][0]);
}

template<int BN>
__device__ __forceinline__ void mfma_pipe(const unsigned short* A, long long ga0, long long ga1,
                                          const unsigned short* BT, int n0, int Kdim,
                                          unsigned short (*As)[BK], unsigned short (*Bs)[BK],
                                          floatx4 (*acc)[BN / 32], int tid) {
  constexpr int NB = BN / 32;               // B fragments per wave
  int wave = tid >> 6, lane = tid & 63;
  int r16 = lane >> 2, c16 = lane & 3;
  int lrow = lane & 15, quad = lane >> 4;
  int wm = (wave & 1) * 64, wn = (wave >> 1) * (BN / 2);
  int NT = Kdim / BK;
  int sw8 = (c16 ^ ((r16 >> 1) & 3)) * 8;   // pre-swizzled global k-chunk (involution)
  int swr = (quad ^ ((lrow >> 1) & 3)) * 8; // swizzled ds_read column
  long long gb0 = (long long)(n0 + wave * 32 + r16) * Kdim;
  long long gb1 = gb0 + 16LL * Kdim;
  // prologue: stage tiles 0 and 1
  stage_tile<BN>(A, ga0, ga1, BT, gb0, gb1, 0, As, Bs, wave, sw8);
  stage_tile<BN>(A, ga0, ga1, BT, gb0, gb1, BK, As + 128, Bs + BN, wave, sw8);
  int cur = 0, nxt = 2;
  for (int t = 0; t < NT; ++t) {
    // drain tile t's loads (own); leave tile t+1's in flight
    if (t == NT - 1) {
      asm volatile("s_waitcnt vmcnt(0)" ::: "memory");
    } else {
      asm volatile("s_waitcnt vmcnt(4)" ::: "memory");
    }
    __builtin_amdgcn_s_barrier();          // all waves' tile-t stages now visible
    if (t + 2 < NT)
      stage_tile<BN>(A, ga0, ga1, BT, gb0, gb1, (t + 2) * BK,
                     As + nxt * 128, Bs + nxt * BN, wave, sw8);
    unsigned short (*Ac)[BK] = As + cur * 128;
    unsigned short (*Bc)[BK] = Bs + cur * BN;
    short8 af[4], bfr[NB];
#pragma unroll
    for (int i = 0; i < 4; ++i) af[i] = *(const short8*)&Ac[wm + i * 16 + lrow][swr];
#pragma unroll
    for (int j = 0; j < NB; ++j) bfr[j] = *(const short8*)&Bc[wn + j * 16 + lrow][swr];
#pragma unroll
    for (int i = 0; i < 4; ++i)
#pragma unroll
      for (int j = 0; j < NB; ++j)
        acc[i][j] = __builtin_amdgcn_mfma_f32_16x16x32_bf16(af[i], bfr[j], acc[i][j], 0, 0, 0);
    cur = (cur == 2) ? 0 : cur + 1;
    nxt = (nxt == 2) ? 0 : nxt + 1;
  }
  __syncthreads();   // protect LDS (union reuse / last-tile reads) before epilogue
}

// ---- 8-wave (512-thread) 128x128 form: 2m x 4n waves, acc[4][2], 8 MFMA/iter ----
// Staging: 1 A + 1 B ld16 per wave per tile (rows wave*16..+16 each). Counted
// vmcnt(2) leaves the next tile's 2 loads in flight. 4 waves/SIMD at 2 blocks/CU.
__device__ __forceinline__ void mfma_pipe8(const unsigned short* A, long long ga,
                                           const unsigned short* BT, int n0, int Kdim,
                                           unsigned short (*As)[BK], unsigned short (*Bs)[BK],
                                           floatx4 (*acc)[2], int tid) {
  int wave = tid >> 6, lane = tid & 63;
  int r16 = lane >> 2, c16 = lane & 3;
  int lrow = lane & 15, quad = lane >> 4;
  int wm = (wave & 1) * 64, wn = (wave >> 1) * 32;
  int NT = Kdim / BK;
  int sw8 = (c16 ^ ((r16 >> 1) & 3)) * 8;
  int swr = (quad ^ ((lrow >> 1) & 3)) * 8;
  long long gb = (long long)(n0 + wave * 16 + r16) * Kdim;
  // prologue: stage tiles 0 and 1
  ld16(A + ga + sw8, &As[wave * 16][0]);
  ld16(BT + gb + sw8, &Bs[wave * 16][0]);
  ld16(A + ga + BK + sw8, &As[128 + wave * 16][0]);
  ld16(BT + gb + BK + sw8, &Bs[128 + wave * 16][0]);
  int cur = 0, nxt = 2;
  for (int t = 0; t < NT; ++t) {
    if (t == NT - 1) asm volatile("s_waitcnt vmcnt(0)" ::: "memory");
    else             asm volatile("s_waitcnt vmcnt(2)" ::: "memory");
    __builtin_amdgcn_s_barrier();
    if (t + 2 < NT) {
      int k0 = (t + 2) * BK;
      ld16(A + ga + k0 + sw8, &As[nxt * 128 + wave * 16][0]);
      ld16(BT + gb + k0 + sw8, &Bs[nxt * 128 + wave * 16][0]);
    }
    unsigned short (*Ac)[BK] = As + cur * 128;
    unsigned short (*Bc)[BK] = Bs + cur * 128;
    short8 af[4], bfr[2];
#pragma unroll
    for (int i = 0; i < 4; ++i) af[i] = *(const short8*)&Ac[wm + i * 16 + lrow][swr];
#pragma unroll
    for (int j = 0; j < 2; ++j) bfr[j] = *(const short8*)&Bc[wn + j * 16 + lrow][swr];
#pragma unroll
    for (int i = 0; i < 4; ++i)
#pragma unroll
      for (int j = 0; j < 2; ++j)
        acc[i][j] = __builtin_amdgcn_mfma_f32_16x16x32_bf16(af[i], bfr[j], acc[i][j], 0, 0, 0);
    cur = (cur == 2) ? 0 : cur + 1;
    nxt = (nxt == 2) ? 0 : nxt + 1;
  }
  __syncthreads();
}

// ---------- 128x128 MFMA GEMM — 8-wave (FF1: relu->bf16) ----------
__global__ __launch_bounds__(512) void mgemm_kernel(const unsigned short* A,
    const unsigned short* BT, long long boff, unsigned short* Cb, int Ndim, int Kdim) {
  __shared__ __align__(16) unsigned short As[3 * 128][BK];
  __shared__ __align__(16) unsigned short Bs[3 * 128][BK];
  int tid = threadIdx.x;
  int bid = blockIdx.x;
  int m0 = (bid & 63) * 128, n0 = (bid >> 6) * 128;
  int wave = tid >> 6, lane = tid & 63;
  int wm = (wave & 1) * 64, wn = (wave >> 1) * 32;
  int lrow = lane & 15, quad = lane >> 4;
  int r16 = lane >> 2;
  floatx4 acc[4][2];
#pragma unroll
  for (int i = 0; i < 4; ++i)
#pragma unroll
    for (int j = 0; j < 2; ++j) acc[i][j] = (floatx4){0.f, 0.f, 0.f, 0.f};
  long long ga = (long long)(m0 + wave * 16 + r16) * Kdim;
  mfma_pipe8(A, ga, BT + boff, n0, Kdim, As, Bs, acc, tid);
#pragma unroll
  for (int i = 0; i < 4; ++i) {
    int mb = m0 + wm + i * 16 + quad * 4;
#pragma unroll
    for (int j = 0; j < 2; ++j) {
      int ncol = n0 + wn + j * 16 + lrow;
#pragma unroll
      for (int r = 0; r < 4; ++r)
        Cb[(long long)(mb + r) * Ndim + ncol] = f2bf(fmaxf(acc[i][j][r], 0.f));
    }
  }
}

// ---------- 128x64 MFMA GEMM — 512 threads / 8 waves (2m x 4n), 4 waves/SIMD ----------
// mode: 0 f32 store, 1 f32 add into Cf, 3 +PE f32 store, 4 bf16 store
__global__ __launch_bounds__(512) void mgemm64_kernel(const unsigned short* A,
    const unsigned short* BT, long long boff, float* Cf, unsigned short* Cb,
    int Ndim, int Kdim, int mode) {
  __shared__ __align__(16) unsigned short As[3 * 128][BK];
  __shared__ __align__(16) unsigned short Bs[3 * 64][BK];
  int tid = threadIdx.x;
  int bid = blockIdx.x;
  int m0 = (bid & 63) * 128, n0 = (bid >> 6) * 64;
  int wave = tid >> 6, lane = tid & 63;
  int r16 = lane >> 2, c16 = lane & 3;
  int lrow = lane & 15, quad = lane >> 4;
  int wm = (wave & 1) * 64, wn = (wave >> 1) * 16;
  int sw8 = (c16 ^ ((r16 >> 1) & 3)) * 8;
  int swr = (quad ^ ((lrow >> 1) & 3)) * 8;
  const unsigned short* Bp = BT + boff;
  long long ga = (long long)(m0 + wave * 16 + r16) * Kdim;
  long long gb = (long long)(n0 + (wave & 3) * 16 + r16) * Kdim;
  int hasB = wave < 4;
  floatx4 acc[4];
#pragma unroll
  for (int i = 0; i < 4; ++i) acc[i] = (floatx4){0.f, 0.f, 0.f, 0.f};
  int NT = Kdim / BK;
  // prologue: stage tiles 0 and 1
  ld16(A + ga + sw8, &As[wave * 16][0]);
  if (hasB) ld16(Bp + gb + sw8, &Bs[wave * 16][0]);
  ld16(A + ga + BK + sw8, &As[128 + wave * 16][0]);
  if (hasB) ld16(Bp + gb + BK + sw8, &Bs[64 + wave * 16][0]);
  int cur = 0, nxt = 2;
  for (int t = 0; t < NT; ++t) {
    if (t == NT - 1)  asm volatile("s_waitcnt vmcnt(0)" ::: "memory");
    else if (hasB)    asm volatile("s_waitcnt vmcnt(2)" ::: "memory");
    else              asm volatile("s_waitcnt vmcnt(1)" ::: "memory");
    __builtin_amdgcn_s_barrier();
    if (t + 2 < NT) {
      int k0 = (t + 2) * BK;
      ld16(A + ga + k0 + sw8, &As[nxt * 128 + wave * 16][0]);
      if (hasB) ld16(Bp + gb + k0 + sw8, &Bs[nxt * 64 + wave * 16][0]);
    }
    unsigned short (*Ac)[BK] = As + cur * 128;
    unsigned short (*Bc)[BK] = Bs + cur * 64;
    short8 af[4];
#pragma unroll
    for (int i = 0; i < 4; ++i) af[i] = *(const short8*)&Ac[wm + i * 16 + lrow][swr];
    short8 bfr = *(const short8*)&Bc[wn + lrow][swr];
#pragma unroll
    for (int i = 0; i < 4; ++i)
      acc[i] = __builtin_amdgcn_mfma_f32_16x16x32_bf16(af[i], bfr, acc[i], 0, 0, 0);
    cur = (cur == 2) ? 0 : cur + 1;
    nxt = (nxt == 2) ? 0 : nxt + 1;
  }
#pragma unroll
  for (int i = 0; i < 4; ++i) {
    int mb = m0 + wm + i * 16 + quad * 4;
    int ncol = n0 + wn + lrow;
#pragma unroll
    for (int r = 0; r < 4; ++r) {
      int m = mb + r;
      long long idx = (long long)m * Ndim + ncol;
      float v = acc[i][r];
      if (mode == 1) Cf[idx] += v;
      else if (mode == 4) Cb[idx] = f2bf(v);
      else if (mode == 3) {
        int t = m & (T_ - 1);
        float freq = __expf(-(float)(ncol & ~1) * (9.210340371976184f / (float)D_));
        float ang = (float)t * freq;
        v += (ncol & 1) ? cosf(ang) : sinf(ang);
        Cf[idx] = v;
      } else Cf[idx] = v;
    }
  }
}

// ---------- QKV GEMM — 8-wave: Q direct; K/V via LDS transpose -> coalesced stores ----------
__global__ __launch_bounds__(512) void qkvgemm_kernel(const unsigned short* A,
    const unsigned short* BT, long long boff, unsigned short* QB,
    unsigned short* KSg, unsigned short* VTSg) {
  __shared__ __align__(16) union {
    struct { unsigned short As[3 * 128][BK]; unsigned short Bs[3 * 128][BK]; } s;
    unsigned short T[128][136];
  } sm;
  int tid = threadIdx.x;
  int bid = blockIdx.x;
  int m0 = (bid & 63) * 128;
  int nt = bid >> 6;
  int n0 = nt * 128;
  int wave = tid >> 6, lane = tid & 63;
  int wm = (wave & 1) * 64, wn = (wave >> 1) * 32;
  int lrow = lane & 15, quad = lane >> 4;
  int r16 = lane >> 2;
  floatx4 acc[4][2];
#pragma unroll
  for (int i = 0; i < 4; ++i)
#pragma unroll
    for (int j = 0; j < 2; ++j) acc[i][j] = (floatx4){0.f, 0.f, 0.f, 0.f};
  long long ga = (long long)(m0 + wave * 16 + r16) * D_;
  mfma_pipe8(A, ga, BT + boff, n0, D_, sm.s.As, sm.s.Bs, acc, tid);
  int b = m0 >> 10, tt = (m0 >> 7) & 7;
  if (nt < 4) {
#pragma unroll
    for (int i = 0; i < 4; ++i) {
      int mb = m0 + wm + i * 16 + quad * 4;
#pragma unroll
      for (int j = 0; j < 2; ++j) {
        int ncol = n0 + wn + j * 16 + lrow;
#pragma unroll
        for (int r = 0; r < 4; ++r)
          QB[(long long)(mb + r) * 512 + ncol] = f2bf(acc[i][j][r]);
      }
    }
  } else if (nt < 8) {
#pragma unroll
    for (int i = 0; i < 4; ++i)
#pragma unroll
      for (int j = 0; j < 2; ++j)
#pragma unroll
        for (int r = 0; r < 4; ++r)
          sm.T[wm + i * 16 + quad * 4 + r][wn + j * 16 + lrow] = f2bf(acc[i][j][r]);
    __syncthreads();
    int tk = tid & 127, hg0 = tid >> 7;    // hg0 in 0..3
#pragma unroll
    for (int p = 0; p < 4; ++p) {
      int hg = p * 4 + hg0;
      int h2 = hg >> 3, g = hg & 7;
      uint4 u = *(const uint4*)&sm.T[tk][h2 * 64 + g * 8];
      int headg = (nt - 4) * 2 + h2;
      long long dst = (((((long long)(b * 8 + headg)) * 8 + tt) * 8 + g) * 128 + tk) * 8;
      *(uint4*)&KSg[dst] = u;
    }
  } else {
#pragma unroll
    for (int i = 0; i < 4; ++i)
#pragma unroll
      for (int j = 0; j < 2; ++j)
#pragma unroll
        for (int r = 0; r < 4; ++r)
          sm.T[wn + j * 16 + lrow][wm + i * 16 + quad * 4 + r] = f2bf(acc[i][j][r]);
    __syncthreads();
    int col = tid & 127, gh = tid >> 7;    // gh in 0..3
    int h2 = col >> 6, ch = col & 63;
    int headg = (nt - 8) * 2 + h2;
    long long base = ((((long long)(b * 8 + headg)) * 8 + tt) * 16);
#pragma unroll
    for (int p = 0; p < 4; ++p) {
      int g = p * 4 + gh;
      uint4 u = *(const uint4*)&sm.T[col][g * 8];
      long long dst = ((base + g) * 64 + ch) * 8;
      *(uint4*)&VTSg[dst] = u;
    }
  }
}

// ---------- flash MFMA attention: barrier-free, early-issue load schedule ----------
// Round-2 structure with load issue points hoisted so every global load has a
// VALU/MFMA phase covering its latency (T14). Proven: fattn ~44us.
__global__ __launch_bounds__(256) void fattn_kernel(const unsigned short* QB,
    const unsigned short* KSg, const unsigned short* VTSg, const int* lens,
    unsigned short* ao) {
  __shared__ __align__(16) unsigned short Ps[64 * 128];
  int blk = blockIdx.x;                     // 1024 blocks = 16 qt x 64 bh
  int swz = (blk & 7) * 128 + (blk >> 3);   // XCD-contiguous: 128 logical blocks/XCD
  int qt = swz & 15, bh = swz >> 4;
  int b = bh >> 3, h = bh & 7;
  int tid = threadIdx.x, wave = tid >> 6, lane = tid & 63;
  int c = lane & 15, quad = lane >> 4;
  int len = lens[b];
  short8 qf[2];
#pragma unroll
  for (int ks = 0; ks < 2; ++ks)
    qf[ks] = *(const short8*)&QB[(long long)(b * 1024 + qt * 64 + wave * 16 + c) * 512
                                 + h * 64 + ks * 32 + quad * 8];
  floatx4 accO[4];
  float lr[4];
#pragma unroll
  for (int j = 0; j < 4; ++j) { accO[j] = (floatx4){0.f, 0.f, 0.f, 0.f}; lr[j] = 0.f; }
  int nkt = (len + 127) >> 7;
  const unsigned short* kp = KSg + (long long)bh * 65536;
  const unsigned short* vp = VTSg + (long long)bh * 65536;
  int kb = (quad * 128 + c) * 8;            // K frag base; +j*128 per j, +4096 for hb=1
  int vbase = quad * 512 + c * 8;           // V frag base; +X*2048 +jn*128
  int row = wave * 16 + c;
  short8 kA[8], kB[8], vA[8], vB[8];
  // preload K(kt=0) jh0 -> kA
#pragma unroll
  for (int j2 = 0; j2 < 4; ++j2) {
    kA[j2]     = *(const short8*)&kp[kb + j2 * 128];
    kA[4 + j2] = *(const short8*)&kp[kb + 4096 + j2 * 128];
  }
  for (int kt = 0; kt < nkt; ++kt) {
    int kbase = kt * 128;
    const unsigned short* kpc = kp + kt * 8192;
    const unsigned short* vpc = vp + kt * 8192;
    const unsigned short* kpn = kpc + 8192;
    int more = (kt + 1 < nkt);
    // issue K jh1 -> kB (covered by QK jh0 + softmax jh0)
#pragma unroll
    for (int j2 = 0; j2 < 4; ++j2) {
      kB[j2]     = *(const short8*)&kpc[kb + (4 + j2) * 128];
      kB[4 + j2] = *(const short8*)&kpc[kb + 4096 + (4 + j2) * 128];
    }
    // ---- QK jh0 (kA) ----
    floatx4 s0[4];
#pragma unroll
    for (int j2 = 0; j2 < 4; ++j2) s0[j2] = (floatx4){0.f, 0.f, 0.f, 0.f};
#pragma unroll
    for (int j2 = 0; j2 < 4; ++j2) {
      s0[j2] = __builtin_amdgcn_mfma_f32_16x16x32_bf16(qf[0], kA[j2], s0[j2], 0, 0, 0);
      s0[j2] = __builtin_amdgcn_mfma_f32_16x16x32_bf16(qf[1], kA[4 + j2], s0[j2], 0, 0, 0);
    }
    // issue V kh0 -> vA (covered by softmax jh0 + QK jh1)
#pragma unroll
    for (int q = 0; q < 8; ++q)
      vA[q] = *(const short8*)&vpc[(q >> 2) * 2048 + (q & 3) * 128 + vbase];
    // softmax jh0 -> Ps cols 0..63
#pragma unroll
    for (int r = 0; r < 4; ++r) {
      int prow = wave * 16 + quad * 4 + r;
      int rx = quad * 4 + r;
#pragma unroll
      for (int j2 = 0; j2 < 4; ++j2) {
        int col = j2 * 16 + c;
        float s = s0[j2][r] * 0.125f;
        s = (kbase + col < len) ? s : -100.f;
        float p = __expf(s);
        lr[r] += p;
        Ps[prow * 128 + (((col >> 3) ^ rx) * 8) + (col & 7)] = f2bf(p);
      }
    }
    // ---- QK jh1 (kB) ----
    floatx4 s1[4];
#pragma unroll
    for (int j2 = 0; j2 < 4; ++j2) s1[j2] = (floatx4){0.f, 0.f, 0.f, 0.f};
#pragma unroll
    for (int j2 = 0; j2 < 4; ++j2) {
      s1[j2] = __builtin_amdgcn_mfma_f32_16x16x32_bf16(qf[0], kB[j2], s1[j2], 0, 0, 0);
      s1[j2] = __builtin_amdgcn_mfma_f32_16x16x32_bf16(qf[1], kB[4 + j2], s1[j2], 0, 0, 0);
    }
    // issue V kh1 -> vB (covered by softmax jh1)
#pragma unroll
    for (int q = 0; q < 8; ++q)
      vB[q] = *(const short8*)&vpc[(2 + (q >> 2)) * 2048 + (q & 3) * 128 + vbase];
    // softmax jh1 -> Ps cols 64..127
#pragma unroll
    for (int r = 0; r < 4; ++r) {
      int prow = wave * 16 + quad * 4 + r;
      int rx = quad * 4 + r;
#pragma unroll
      for (int j2 = 0; j2 < 4; ++j2) {
        int col = (4 + j2) * 16 + c;
        float s = s1[j2][r] * 0.125f;
        s = (kbase + col < len) ? s : -100.f;
        float p = __expf(s);
        lr[r] += p;
        Ps[prow * 128 + (((col >> 3) ^ rx) * 8) + (col & 7)] = f2bf(p);
      }
    }
    // ---- PV kh0 (vA) ----
#pragma unroll
    for (int kk2 = 0; kk2 < 2; ++kk2) {
      short8 pa = *(const short8*)&Ps[row * 128 + (((kk2 * 4 + quad) ^ c) * 8)];
#pragma unroll
      for (int jn = 0; jn < 4; ++jn)
        accO[jn] = __builtin_amdgcn_mfma_f32_16x16x32_bf16(pa, vA[kk2 * 4 + jn], accO[jn], 0, 0, 0);
    }
    // issue next K jh0 -> kA (vA dead; covered by PV kh1)
    if (more) {
#pragma unroll
      for (int j2 = 0; j2 < 4; ++j2) {
        kA[j2]     = *(const short8*)&kpn[kb + j2 * 128];
        kA[4 + j2] = *(const short8*)&kpn[kb + 4096 + j2 * 128];
      }
    }
    // ---- PV kh1 (vB) ----
#pragma unroll
    for (int kk2 = 0; kk2 < 2; ++kk2) {
      int kk = 2 + kk2;
      short8 pa = *(const short8*)&Ps[row * 128 + (((kk * 4 + quad) ^ c) * 8)];
#pragma unroll
      for (int jn = 0; jn < 4; ++jn)
        accO[jn] = __builtin_amdgcn_mfma_f32_16x16x32_bf16(pa, vB[kk2 * 4 + jn], accO[jn], 0, 0, 0);
    }
  }
  // deferred row-reduce, normalize + store
#pragma unroll
  for (int r = 0; r < 4; ++r) {
    float ls = lr[r];
    ls += __shfl_xor(ls, 1, 64);
    ls += __shfl_xor(ls, 2, 64);
    ls += __shfl_xor(ls, 4, 64);
    ls += __shfl_xor(ls, 8, 64);
    float inv = 1.f / ls;
    long long token = b * 1024 + qt * 64 + wave * 16 + quad * 4 + r;
#pragma unroll
    for (int jn = 0; jn < 4; ++jn)
      ao[token * 512 + h * 64 + jn * 16 + c] = f2bf(accO[jn][r] * inv);
  }
}

// ---------- argmin GEMM over COMPACTED rows: dist = enorm[v] - 2*(Z[idx].ET^T) ----------
__global__ __launch_bounds__(256) void dgemm_argmin(const unsigned short* Z, const int* ridx,
    const int* cnt, const unsigned short* ET, const float* en, unsigned long long* best) {
  __shared__ __align__(16) union {
    struct { unsigned short A[3 * 128][BK]; unsigned short B[3 * 128][BK]; } s;
    unsigned long long part[128][33];
  } sm;
  int m0 = blockIdx.y * 128;
  int na = *cnt;
  if (m0 >= ((na + 127) & ~127)) return;
  int tid = threadIdx.x;
  int n0 = blockIdx.x * 128;
  int wave = tid >> 6, lane = tid & 63;
  int wm = (wave & 1) * 64, wn = (wave >> 1) * 64;
  int lrow = lane & 15, quad = lane >> 4;
  int r16 = lane >> 2;
  int slot = (wave >> 1) * 16 + lrow;
  floatx4 acc[4][4];
#pragma unroll
  for (int i = 0; i < 4; ++i)
#pragma unroll
    for (int j = 0; j < 4; ++j) acc[i][j] = (floatx4){0.f, 0.f, 0.f, 0.f};
  long long ga0 = (long long)ridx[m0 + wave * 32 + r16] * D_;
  long long ga1 = (long long)ridx[m0 + wave * 32 + 16 + r16] * D_;
  mfma_pipe<128>(Z, ga0, ga1, ET, n0, D_, sm.s.A, sm.s.B, acc, tid);
  float env[4];
#pragma unroll
  for (int j = 0; j < 4; ++j) env[j] = en[n0 + wn + j * 16 + lrow];
#pragma unroll
  for (int i = 0; i < 4; ++i) {
#pragma unroll
    for (int r = 0; r < 4; ++r) {
      int rowl = wm + i * 16 + quad * 4 + r;
      unsigned long long bl = ~0ull;
#pragma unroll
      for (int j = 0; j < 4; ++j) {
        float v = env[j] - 2.f * acc[i][j][r];
        unsigned long long pk = (((unsigned long long)fkey(v)) << 32) |
                                (unsigned int)(n0 + wn + j * 16 + lrow);
        if (pk < bl) bl = pk;
      }
      sm.part[rowl][(slot + rowl) & 31] = bl;
    }
  }
  __syncthreads();
  if (tid < 128) {
    unsigned long long bb = sm.part[tid][0];
#pragma unroll 4
    for (int k2 = 1; k2 < 32; ++k2) { unsigned long long o = sm.part[tid][k2]; if (o < bb) bb = o; }
    atomicMin(&best[m0 + tid], bb);
  }
}

// ---------- logits GEMM over COMPACTED rows: fixed-offset LSE + target logit ----------
__global__ __launch_bounds__(256) void lgemm_lse(const unsigned short* OUTB, const int* ridx,
    const int* cnt, const unsigned short* TOPT, const unsigned long long* best,
    float* PS, float* TL) {
  __shared__ __align__(16) union {
    struct { unsigned short A[3 * 128][BK]; unsigned short B[3 * 128][BK]; } s;
    float part[128][33];
  } sm;
  int m0 = blockIdx.y * 128;
  int na = *cnt;
  if (m0 >= ((na + 127) & ~127)) return;
  int tid = threadIdx.x;
  int n0 = blockIdx.x * 128;
  int wave = tid >> 6, lane = tid & 63;
  int wm = (wave & 1) * 64, wn = (wave >> 1) * 64;
  int lrow = lane & 15, quad = lane >> 4;
  int r16 = lane >> 2;
  int slot = (wave >> 1) * 16 + lrow;
  floatx4 acc[4][4];
#pragma unroll
  for (int i = 0; i < 4; ++i)
#pragma unroll
    for (int j = 0; j < 4; ++j) acc[i][j] = (floatx4){0.f, 0.f, 0.f, 0.f};
  long long ga0 = (long long)ridx[m0 + wave * 32 + r16] * D_;
  long long ga1 = (long long)ridx[m0 + wave * 32 + 16 + r16] * D_;
  mfma_pipe<128>(OUTB, ga0, ga1, TOPT, n0, D_, sm.s.A, sm.s.B, acc, tid);
#pragma unroll
  for (int i = 0; i < 4; ++i) {
#pragma unroll
    for (int r = 0; r < 4; ++r) {
      int rowl = wm + i * 16 + quad * 4 + r;
      int tg = (int)(best[m0 + rowl] & 0xffffffffu);
      float ss = 0.f;
#pragma unroll
      for (int j = 0; j < 4; ++j) {
        float v = acc[i][j][r];
        ss += __expf(v);
        if (n0 + wn + j * 16 + lrow == tg) TL[m0 + rowl] = v;
      }
      sm.part[rowl][(slot + rowl) & 31] = ss;
    }
  }
  __syncthreads();
  if (tid < 128) {
    float S = 0.f;
#pragma unroll 4
    for (int k2 = 0; k2 < 32; ++k2) S += sm.part[tid][k2];
    PS[(long long)(m0 + tid) * 64 + blockIdx.x] = S;
  }
}

__global__ void lse_combine(const float* PS, const float* TL, const int* cnt, float* entm) {
  int t = blockIdx.x * 256 + threadIdx.x;   // compact index, grid covers NCAP
  if (t >= NCAP) return;
  if (t < *cnt) {
    float S = 0.f;
    for (int i = 0; i < 64; ++i) S += PS[(long long)t * 64 + i];
    entm[t] = __logf(S) - TL[t];            // mcomb == 1 for active rows
  } else {
    entm[t] = 0.f;
  }
}

// ---------- layernorm: wave per token, shuffle reductions ----------
__global__ __launch_bounds__(256) void ln_kernel(const float* X, float* Yf, unsigned short* Yb,
                                                 int obf, const float* s, const float* b) {
  int tid = threadIdx.x, wave = tid >> 6, lane = tid & 63;
  long long n = (long long)blockIdx.x * 4 + wave;
  const float* x = X + n * D_ + lane * 8;
  float v[8];
  *(float4*)&v[0] = *(const float4*)x;
  *(float4*)&v[4] = *(const float4*)(x + 4);
  float sum = 0.f;
#pragma unroll
  for (int j = 0; j < 8; ++j) sum += v[j];
  for (int m = 32; m; m >>= 1) sum += __shfl_xor(sum, m, 64);
  float mean = sum * (1.f / (float)D_);
  float vs = 0.f;
#pragma unroll
  for (int j = 0; j < 8; ++j) { v[j] -= mean; vs += v[j] * v[j]; }
  for (int m = 32; m; m >>= 1) vs += __shfl_xor(vs, m, 64);
  float r = rsqrtf(vs * (1.f / (float)D_) + EPS_);
  float sv[8], bv[8];
  *(float4*)&sv[0] = *(const float4*)(s + lane * 8);
  *(float4*)&sv[4] = *(const float4*)(s + lane * 8 + 4);
  *(float4*)&bv[0] = *(const float4*)(b + lane * 8);
  *(float4*)&bv[4] = *(const float4*)(b + lane * 8 + 4);
  if (obf) {
    unsigned short o[8];
#pragma unroll
    for (int j = 0; j < 8; ++j) o[j] = f2bf(v[j] * r * sv[j] + bv[j]);
    *(uint4*)(Yb + n * D_ + lane * 8) = *(const uint4*)o;
  } else {
    float o[8];
#pragma unroll
    for (int j = 0; j < 8; ++j) o[j] = v[j] * r * sv[j] + bv[j];
    *(float4*)(Yf + n * D_ + lane * 8) = *(const float4*)&o[0];
    *(float4*)(Yf + n * D_ + lane * 8 + 4) = *(const float4*)&o[4];
  }
}

// ---------- masked_xs ----------
__global__ void maskapply_kernel(float* x, const int* maski, const float* memb) {
  long long i = (long long)blockIdx.x * 256 + threadIdx.x;
  int n = (int)(i >> 9), d = (int)(i & 511);
  if (maski[n]) x[i] = memb[d];
}

// ---------- final reduce + dual-dtype write ----------
__global__ void final_kernel(const float* entm, const float* mcomb, void* out) {
  __shared__ float r1[256], r2[256];
  int tid = threadIdx.x;
  float s1 = 0.f, s2 = 0.f;
  for (int i = tid; i < NCAP; i += 256) s1 += entm[i];
  for (int i = tid; i < NTOK; i += 256) s2 += mcomb[i];
  r1[tid] = s1; r2[tid] = s2;
  __syncthreads();
  for (int st = 128; st > 0; st >>= 1) {
    if (tid < st) { r1[tid] += r1[tid + st]; r2[tid] += r2[tid + st]; }
    __syncthreads();
  }
  if (tid == 0) {
    float loss = r1[0] / r2[0];
    unsigned short b16 = f2bf(loss);
    unsigned short* o = (unsigned short*)out;
    o[0] = b16; o[1] = b16;
  }
}

extern "C" void kernel_launch(void* const* d_in, const int* in_sizes, int n_in,
                              void* d_out, int out_size, void* d_ws, size_t ws_size,
                              hipStream_t stream) {
  if (n_in < 20) return;
  float* wsf = (float*)d_ws;
  int* flags = (int*)d_ws;
  const long long OF_P = 256;
  const long long OF_X = 16640;
  const long long OF_HB = OF_X + 4194304;
  const long long OF_BIG = OF_HB + 2097152;
  const long long OF_AOB = OF_BIG + 8388608;
  const long long OF_WT = OF_AOB + 2097152;
  const long long OF_TOPT = OF_WT + 9699328;
  const long long OF_EMBT = OF_TOPT + 2097152;
  const long long OF_EN = OF_EMBT + 2097152;
  const long long OF_BEST = OF_EN + 8192;          // NCAP u64 = 4096 floats
  const long long OF_PS = OF_BEST + 4096;          // NCAP*64 floats
  const long long OF_TL = OF_PS + 131072;          // NCAP
  const long long OF_MI = OF_TL + 2048;
  const long long OF_MC = OF_MI + 8192;
  const long long OF_EM = OF_MC + 8192;            // NCAP
  const long long OF_CNT = OF_EM + 2048;
  const long long OF_IDX = OF_CNT + 16;            // NCAP ints
  const long long END = OF_IDX + 2048;
  if (ws_size < (size_t)END * 4) return;

  float* X = wsf + OF_X;
  unsigned short* HB = (unsigned short*)(wsf + OF_HB);
  unsigned short* BIGB = (unsigned short*)(wsf + OF_BIG);
  unsigned short* AOB = (unsigned short*)(wsf + OF_AOB);
  unsigned short* WT = (unsigned short*)(wsf + OF_WT);
  unsigned short* TOPT = (unsigned short*)(wsf + OF_TOPT);
  unsigned short* EMBT = (unsigned short*)(wsf + OF_EMBT);
  float* EN = wsf + OF_EN;
  unsigned long long* BEST = (unsigned long long*)(wsf + OF_BEST);
  float* PS = wsf + OF_PS;
  float* TL = wsf + OF_TL;
  int* MI = (int*)(wsf + OF_MI);
  float* MC = wsf + OF_MC;
  float* EM = wsf + OF_EM;
  int* CNT = (int*)(wsf + OF_CNT);
  int* IDX = (int*)(wsf + OF_IDX);
  float* P = wsf + OF_P;
  float* ln1s = P, *ln1b = P + 3072, *ln2s = P + 6144, *ln2b = P + 9216;
  float* ans = P + 12288, *anb = P + 12800, *ilns = P + 13312, *ilnb = P + 13824;
  float* memb = P + 14336;

  unsigned short* QB = BIGB;
  unsigned short* KSg = BIGB + 4194304;
  unsigned short* VTSg = BIGB + 8388608;

  const long long W_QKV = 0, W_O = 4718592, W_1 = 6291456, W_2 = 12582912,
                  W_EMB = 18874368, W_PRJ = 19136512;

  detect_kernel<<<1, 256, 0, stream>>>((const unsigned int*)d_in[0],
                                       (const unsigned int*)d_in[2], flags);
  hipMemsetAsync((void*)BEST, 0xFF, NCAP * 8, stream);
  hipMemsetAsync((void*)EN, 0, V_ * 4, stream);
  hipMemsetAsync((void*)CNT, 0, 16, stream);
  hipMemsetAsync((void*)IDX, 0, NCAP * 4, stream);
  conv_all_kernel<<<58, 256, 0, stream>>>(d_in[4], d_in[5], d_in[8], d_in[9], d_in[12],
                                          d_in[13], d_in[14], d_in[15], d_in[16], P, flags);
  prep_kernel<<<32, 256, 0, stream>>>(d_in[2], (const int*)d_in[1], MI, MC, IDX, CNT, flags);

  unsigned short* XSB = BIGB;
  convb_kernel<<<16384, 256, 0, stream>>>(d_in[0], XSB, 4194304, flags);

  trans_kernel<<<dim3(48, 16, 6), 256, 0, stream>>>(d_in[6], WT + W_QKV, 512, 1536, flags);
  trans_kernel<<<dim3(16, 16, 6), 256, 0, stream>>>(d_in[7], WT + W_O, 512, 512, flags);
  trans_kernel<<<dim3(64, 16, 6), 256, 0, stream>>>(d_in[10], WT + W_1, 512, 2048, flags);
  trans_kernel<<<dim3(16, 64, 6), 256, 0, stream>>>(d_in[11], WT + W_2, 2048, 512, flags);
  trans_kernel<<<dim3(16, 16, 1), 256, 0, stream>>>(d_in[3], WT + W_EMB, 512, 512, flags);
  trans_kernel<<<dim3(16, 16, 1), 256, 0, stream>>>(d_in[18], WT + W_PRJ, 512, 512, flags);
  trans_big_kernel<<<dim3(256, 16, 2), 256, 0, stream>>>(d_in[17], d_in[19], TOPT, EMBT,
                                                         EN, flags);

  dim3 gC(64, NCAP / 128);   // compacted V-GEMMs: 16 row-tiles, device-side early exit

  // x = xs @ W_embed + PE
  mgemm64_kernel<<<512, 512, 0, stream>>>(XSB, WT + W_EMB, 0, X, nullptr, 512, 512, 3);
  // target ids (needed only for masked&padded tokens -> compacted)
  ln_kernel<<<2048, 256, 0, stream>>>(X, nullptr, HB, 1, ilns, ilnb);
  mgemm64_kernel<<<512, 512, 0, stream>>>(HB, WT + W_PRJ, 0, nullptr, AOB, 512, 512, 4);
  dgemm_argmin<<<gC, 256, 0, stream>>>(AOB, IDX, CNT, EMBT, EN, BEST);
  maskapply_kernel<<<16384, 256, 0, stream>>>(X, MI, memb);

  for (int l = 0; l < L_; ++l) {
    ln_kernel<<<2048, 256, 0, stream>>>(X, nullptr, HB, 1, ln1s + l * 512, ln1b + l * 512);
    qkvgemm_kernel<<<768, 512, 0, stream>>>(HB, WT + W_QKV, (long long)l * 786432,
                                            QB, KSg, VTSg);
    fattn_kernel<<<1024, 256, 0, stream>>>(QB, KSg, VTSg, (const int*)d_in[1], AOB);
    mgemm64_kernel<<<512, 512, 0, stream>>>(AOB, WT + W_O, (long long)l * 262144,
                                            X, nullptr, 512, 512, 1);
    ln_kernel<<<2048, 256, 0, stream>>>(X, nullptr, HB, 1, ln2s + l * 512, ln2b + l * 512);
    mgemm_kernel<<<1024, 512, 0, stream>>>(HB, WT + W_1, (long long)l * 1048576,
                                           BIGB, 2048, 512);
    mgemm64_kernel<<<512, 512, 0, stream>>>(BIGB, WT + W_2, (long long)l * 1048576,
                                            X, nullptr, 512, 2048, 1);
  }
  ln_kernel<<<2048, 256, 0, stream>>>(X, nullptr, AOB, 1, ans, anb);
  lgemm_lse<<<gC, 256, 0, stream>>>(AOB, IDX, CNT, TOPT, BEST, PS, TL);
  lse_combine<<<8, 256, 0, stream>>>(PS, TL, CNT, EM);
  final_kernel<<<1, 256, 0, stream>>>(EM, MC, d_out);
}